// Round 7
// baseline (1405.205 us; speedup 1.0000x reference)
//
#include <hip/hip_runtime.h>
#include <hip/hip_bf16.h>
#include <math.h>

#define CH 64
#define NPOS 9216   // 96*96
#define NTOT 18432  // 2*9216
#define KSPLIT 8
#define KCHUNK 1152 // 9216/8

typedef short bf16x8 __attribute__((ext_vector_type(8)));
typedef float f32x4 __attribute__((ext_vector_type(4)));

__device__ __forceinline__ float bf2f(short s) {
  unsigned int u = ((unsigned int)(unsigned short)s) << 16;
  return __builtin_bit_cast(float, u);
}
__device__ __forceinline__ short f2bf(float f) {
  unsigned int u = __builtin_bit_cast(unsigned int, f);
  unsigned int r = (u + 0x7fffu + ((u >> 16) & 1u)) >> 16;  // RNE
  return (short)r;
}
__device__ __forceinline__ float gelu_exact(float x) {
  return 0.5f * x * (1.f + erff(x * 0.70710678118654752440f));
}

// OUTPUT IS FLOAT32 (reference is pure fp32; harness contract "else float*").
// R2-R5's bit-identical absmax 6.765625 was the checker pairing our bf16 shorts
// into f32 words: max|ref[2j+1]-ref[j]| over 0.59M iid N(0,2) = 6.77. Inputs
// are fp32 (R1 NaN vs R2 finite A/B). Layout is plain NCHW (R6 transpose A/B).

// ---------------- Kernel A: LN1 + QKV projection ----------------
// grid (72, 3) x 256. Writes Q/K/V bf16 in [b*N+n][c] layout.
__global__ __launch_bounds__(256) void k_ln_qkv(
    const float* __restrict__ x, const float* __restrict__ ln1w, const float* __restrict__ ln1b,
    const float* __restrict__ qw, const float* __restrict__ qb,
    const float* __restrict__ kw, const float* __restrict__ kb,
    const float* __restrict__ vw, const float* __restrict__ vb,
    short* __restrict__ Qg, short* __restrict__ Kg, short* __restrict__ Vg) {
  __shared__ float Wm[4096];
  __shared__ float bias[64], lw[64], lb[64];
  int mat = blockIdx.y;
  const float* wsrc = (mat == 0) ? qw : (mat == 1) ? kw : vw;
  const float* bsrc = (mat == 0) ? qb : (mat == 1) ? kb : vb;
  for (int i = threadIdx.x; i < 4096; i += 256) Wm[i] = wsrc[i];
  if (threadIdx.x < 64) {
    bias[threadIdx.x] = bsrc[threadIdx.x];
    lw[threadIdx.x] = ln1w[threadIdx.x];
    lb[threadIdx.x] = ln1b[threadIdx.x];
  }
  __syncthreads();
  int idx = blockIdx.x * 256 + threadIdx.x;
  int b = idx / NPOS, n = idx % NPOS;
  const float* xb = x + (size_t)b * CH * NPOS + n;
  float xr[64];
  float mu = 0.f;
#pragma unroll
  for (int c = 0; c < 64; ++c) { float v = xb[c * NPOS]; xr[c] = v; mu += v; }
  mu *= (1.f / 64.f);
  float var = 0.f;
#pragma unroll
  for (int c = 0; c < 64; ++c) { float d = xr[c] - mu; var += d * d; }
  float rstd = rsqrtf(var * (1.f / 64.f) + 1e-5f);
#pragma unroll
  for (int c = 0; c < 64; ++c) xr[c] = (xr[c] - mu) * rstd * lw[c] + lb[c];
  short* outp = ((mat == 0) ? Qg : (mat == 1) ? Kg : Vg) + (size_t)idx * 64;
  for (int o = 0; o < 64; ++o) {
    float acc = bias[o];
    const float* wrow = &Wm[o * 64];
#pragma unroll
    for (int c = 0; c < 64; ++c) acc += wrow[c] * xr[c];
    outp[o] = f2bf(acc);
  }
}

// ---------------- Kernel B1: pure-VALU attention, split-K partials ----------------
__global__ __launch_bounds__(256) void k_attn_part(
    const short* __restrict__ Qg, const short* __restrict__ Kg, const short* __restrict__ Vg,
    short* __restrict__ OPo, float* __restrict__ OPl) {
  __shared__ float Kl[4096];  // [key][ch] f32
  __shared__ float Vl[4096];
  int q_idx = blockIdx.x * 256 + threadIdx.x;
  int b = q_idx / NPOS;
  int ks = blockIdx.y;
  f32x4 q4[16];
  {
    const short* qp = Qg + (size_t)q_idx * 64;
#pragma unroll
    for (int c4 = 0; c4 < 16; ++c4) {
      f32x4 v;
#pragma unroll
      for (int j = 0; j < 4; ++j) v[j] = bf2f(qp[c4 * 4 + j]);
      q4[c4] = v;
    }
  }
  f32x4 o4[16];
#pragma unroll
  for (int c4 = 0; c4 < 16; ++c4) o4[c4] = (f32x4){0.f, 0.f, 0.f, 0.f};
  float l = 0.f;

  int row = threadIdx.x >> 2;
  int part = threadIdx.x & 3;

  for (int t = 0; t < 18; ++t) {
    int key0 = ks * KCHUNK + t * 64;
    __syncthreads();
    {
      const short* ksrc = Kg + ((size_t)(b * NPOS + key0 + row)) * 64 + part * 16;
      const short* vsrc = Vg + ((size_t)(b * NPOS + key0 + row)) * 64 + part * 16;
      bf16x8 ka = *(const bf16x8*)ksrc;
      bf16x8 kb2 = *(const bf16x8*)(ksrc + 8);
      bf16x8 va = *(const bf16x8*)vsrc;
      bf16x8 vb2 = *(const bf16x8*)(vsrc + 8);
      float* kd = Kl + row * 64 + part * 16;
      float* vd = Vl + row * 64 + part * 16;
#pragma unroll
      for (int j = 0; j < 8; ++j) { kd[j] = bf2f(ka[j]); kd[8 + j] = bf2f(kb2[j]); }
#pragma unroll
      for (int j = 0; j < 8; ++j) { vd[j] = bf2f(va[j]); vd[8 + j] = bf2f(vb2[j]); }
    }
    __syncthreads();

    for (int j = 0; j < 64; ++j) {
      const f32x4* kr = (const f32x4*)(Kl + j * 64);
      f32x4 sv = (f32x4){0.f, 0.f, 0.f, 0.f};
#pragma unroll
      for (int c4 = 0; c4 < 16; ++c4) sv += q4[c4] * kr[c4];
      float s = sv[0] + sv[1] + sv[2] + sv[3];
      float e = __expf(s);
      l += e;
      const f32x4* vr = (const f32x4*)(Vl + j * 64);
#pragma unroll
      for (int c4 = 0; c4 < 16; ++c4) o4[c4] += e * vr[c4];
    }
  }

  short* op = OPo + ((size_t)q_idx * KSPLIT + ks) * 64;
#pragma unroll
  for (int c4 = 0; c4 < 16; ++c4) {
#pragma unroll
    for (int j = 0; j < 4; ++j) op[c4 * 4 + j] = f2bf(o4[c4][j]);
  }
  OPl[(size_t)q_idx * KSPLIT + ks] = l;
}

// ---------------- Kernel B2: merge split-K partials ----------------
__global__ __launch_bounds__(256) void k_attn_merge(
    const short* __restrict__ OPo, const float* __restrict__ OPl, float* __restrict__ ATT) {
  int q_idx = blockIdx.x * 256 + threadIdx.x;
  float l = 0.f;
#pragma unroll
  for (int s = 0; s < KSPLIT; ++s) l += OPl[(size_t)q_idx * KSPLIT + s];
  float inv = 1.f / l;
  float acc[64];
#pragma unroll
  for (int c = 0; c < 64; ++c) acc[c] = 0.f;
  for (int s = 0; s < KSPLIT; ++s) {
    const short* op = OPo + ((size_t)q_idx * KSPLIT + s) * 64;
#pragma unroll
    for (int c = 0; c < 64; ++c) acc[c] += bf2f(op[c]);
  }
  float* at = ATT + (size_t)q_idx * 64;
#pragma unroll
  for (int c = 0; c < 64; ++c) at[c] = acc[c] * inv;
}

// ---------------- Kernel C: residual + LN2 + proj_in ----------------
__global__ __launch_bounds__(256) void k_res_ln2_proj(
    const float* __restrict__ x, const float* __restrict__ ATT,
    const float* __restrict__ ln2w, const float* __restrict__ ln2b,
    const float* __restrict__ piw,
    float* __restrict__ Hbuf) {
  __shared__ float Wm[1024];
  __shared__ float lw[64], lb[64];
  int part = blockIdx.y;
  for (int i = threadIdx.x; i < 1024; i += 256) Wm[i] = piw[part * 1024 + i];
  if (threadIdx.x < 64) { lw[threadIdx.x] = ln2w[threadIdx.x]; lb[threadIdx.x] = ln2b[threadIdx.x]; }
  __syncthreads();
  int idx = blockIdx.x * 256 + threadIdx.x;
  int b = idx / NPOS, n = idx % NPOS;
  const float* xb = x + (size_t)b * CH * NPOS + n;
  const f32x4* att = (const f32x4*)(ATT + (size_t)idx * 64);
  float xr[64];
  float mu = 0.f;
#pragma unroll
  for (int c4 = 0; c4 < 16; ++c4) {
    f32x4 a = att[c4];
#pragma unroll
    for (int j = 0; j < 4; ++j) {
      int c = c4 * 4 + j;
      float v = xb[c * NPOS] + a[j];
      xr[c] = v;
      mu += v;
    }
  }
  mu *= (1.f / 64.f);
  float var = 0.f;
#pragma unroll
  for (int c = 0; c < 64; ++c) { float d = xr[c] - mu; var += d * d; }
  float rstd = rsqrtf(var * (1.f / 64.f) + 1e-5f);
#pragma unroll
  for (int c = 0; c < 64; ++c) xr[c] = (xr[c] - mu) * rstd * lw[c] + lb[c];
  float* hb = Hbuf + (size_t)b * CH * NPOS + (size_t)part * 16 * NPOS + n;
  for (int oo = 0; oo < 16; ++oo) {
    float acc = 0.f;
#pragma unroll
    for (int c = 0; c < 64; ++c) acc += Wm[oo * 64 + c] * xr[c];
    hb[oo * NPOS] = acc;
  }
}

// ---------------- Kernel D: per-patch spectral filter ----------------
__global__ __launch_bounds__(256) void k_fft(float* __restrict__ Hbuf, const float* __restrict__ fftw) {
  int idx = blockIdx.x * 256 + threadIdx.x;
  int c = idx & 63;
  int patch = idx >> 6;
  int wb = patch % 12;
  int t2 = patch / 12;
  int hb = t2 % 12;
  int b = t2 / 12;
  float* base = Hbuf + (size_t)(b * CH + c) * NPOS + (hb * 8) * 96 + wb * 8;
  const float r = 0.70710678118654752440f;
  const float CO[8] = {1.f, r, 0.f, -r, -1.f, -r, 0.f, r};
  const float SI[8] = {0.f, r, 1.f, r, 0.f, -r, -1.f, -r};
  float Ar[8][5], Ai[8][5];
#pragma unroll
  for (int p = 0; p < 8; ++p) {
    f32x4 ra = *(const f32x4*)(base + p * 96);
    f32x4 rb = *(const f32x4*)(base + p * 96 + 4);
    float row[8] = {ra[0], ra[1], ra[2], ra[3], rb[0], rb[1], rb[2], rb[3]};
#pragma unroll
    for (int v = 0; v < 5; ++v) {
      float sr = 0.f, si = 0.f;
#pragma unroll
      for (int q = 0; q < 8; ++q) {
        int k = (q * v) & 7;
        sr += row[q] * CO[k];
        si -= row[q] * SI[k];
      }
      Ar[p][v] = sr;
      Ai[p][v] = si;
    }
  }
  const float* wp = fftw + c * 40;
#pragma unroll
  for (int v = 0; v < 5; ++v) {
    float Br[8], Bi[8];
#pragma unroll
    for (int u = 0; u < 8; ++u) {
      float cr = 0.f, ci = 0.f;
#pragma unroll
      for (int p = 0; p < 8; ++p) {
        int k = (p * u) & 7;
        float cc = CO[k], ss = SI[k];
        cr += Ar[p][v] * cc + Ai[p][v] * ss;
        ci += Ai[p][v] * cc - Ar[p][v] * ss;
      }
      float wv = wp[u * 5 + v];
      Br[u] = cr * wv;
      Bi[u] = ci * wv;
    }
#pragma unroll
    for (int p = 0; p < 8; ++p) {
      float yr = 0.f, yi = 0.f;
#pragma unroll
      for (int u = 0; u < 8; ++u) {
        int k = (p * u) & 7;
        float cc = CO[k], ss = SI[k];
        yr += Br[u] * cc - Bi[u] * ss;
        yi += Bi[u] * cc + Br[u] * ss;
      }
      Ar[p][v] = yr * 0.125f;
      Ai[p][v] = yi * 0.125f;
    }
  }
#pragma unroll
  for (int p = 0; p < 8; ++p) {
    float outv[8];
#pragma unroll
    for (int q = 0; q < 8; ++q) {
      float acc = Ar[p][0] + ((q & 1) ? -Ar[p][4] : Ar[p][4]);
#pragma unroll
      for (int v = 1; v < 4; ++v) {
        int k = (q * v) & 7;
        acc += 2.f * (Ar[p][v] * CO[k] - Ai[p][v] * SI[k]);
      }
      outv[q] = acc * 0.125f;
    }
    f32x4 wa = {outv[0], outv[1], outv[2], outv[3]};
    f32x4 wb2 = {outv[4], outv[5], outv[6], outv[7]};
    *(f32x4*)(base + p * 96) = wa;
    *(f32x4*)(base + p * 96 + 4) = wb2;
  }
}

// ---------------- Kernel E: dwconv3x3 + gelu-gate + proj_out + residual ----------------
// grid (72, 2) x 256. FLOAT32 output.
__global__ __launch_bounds__(256) void k_dw_out(
    const float* __restrict__ Hbuf, const float* __restrict__ dww,
    const float* __restrict__ poww, const float* __restrict__ x,
    const float* __restrict__ ATT, float* __restrict__ out) {
  __shared__ float dw[576];
  __shared__ float pw[1024];
  int half = blockIdx.y;
  for (int i = threadIdx.x; i < 576; i += 256) dw[i] = dww[i];
  for (int i = threadIdx.x; i < 1024; i += 256) pw[i] = poww[half * 1024 + i];
  __syncthreads();
  int idx = blockIdx.x * 256 + threadIdx.x;
  int b = idx / NPOS, n = idx % NPOS;
  int y = n / 96, xx = n % 96;
  const float* hb = Hbuf + (size_t)b * CH * NPOS;
  float g[32];
#pragma unroll
  for (int cc = 0; cc < 32; ++cc) {
    float d1 = 0.f, d2 = 0.f;
    for (int dy = -1; dy <= 1; ++dy) {
      int yy = y + dy;
      if (yy < 0 || yy >= 96) continue;
      for (int dx = -1; dx <= 1; ++dx) {
        int xv = xx + dx;
        if (xv < 0 || xv >= 96) continue;
        int ki = (dy + 1) * 3 + (dx + 1);
        d1 += hb[(size_t)cc * NPOS + yy * 96 + xv] * dw[cc * 9 + ki];
        d2 += hb[(size_t)(cc + 32) * NPOS + yy * 96 + xv] * dw[(cc + 32) * 9 + ki];
      }
    }
    g[cc] = gelu_exact(d1) * d2;
  }
  const float* xr = x + (size_t)b * CH * NPOS + (size_t)half * 32 * NPOS + n;
  const float* att = ATT + (size_t)idx * 64 + half * 32;
  float* ob = out + (size_t)b * CH * NPOS + (size_t)half * 32 * NPOS + n;
  for (int oo = 0; oo < 32; ++oo) {
    float acc = xr[oo * NPOS] + att[oo];
#pragma unroll
    for (int cg = 0; cg < 32; ++cg) acc += pw[oo * 32 + cg] * g[cg];
    ob[oo * NPOS] = acc;
  }
}

extern "C" void kernel_launch(void* const* d_in, const int* in_sizes, int n_in,
                              void* d_out, int out_size, void* d_ws, size_t ws_size,
                              hipStream_t stream) {
  const float* x    = (const float*)d_in[0];
  const float* ln1w = (const float*)d_in[1];
  const float* ln1b = (const float*)d_in[2];
  const float* ln2w = (const float*)d_in[3];
  const float* ln2b = (const float*)d_in[4];
  const float* qw   = (const float*)d_in[5];
  const float* qb   = (const float*)d_in[6];
  const float* kw   = (const float*)d_in[7];
  const float* kb   = (const float*)d_in[8];
  const float* vw   = (const float*)d_in[9];
  const float* vb   = (const float*)d_in[10];
  const float* fftw = (const float*)d_in[11];
  const float* piw  = (const float*)d_in[12];
  const float* dww  = (const float*)d_in[13];
  const float* poww = (const float*)d_in[14];

  short* Qg = (short*)d_ws;                          // [NTOT][64] bf16
  short* Kg = Qg + (size_t)NTOT * 64;
  short* Vg = Kg + (size_t)NTOT * 64;
  float* ATT  = (float*)(Vg + (size_t)NTOT * 64);    // [NTOT][64] f32
  float* Hbuf = ATT + (size_t)NTOT * 64;             // [b][c][n] f32
  short* OPo  = (short*)(Hbuf + (size_t)NTOT * 64);  // [NTOT][KSPLIT][64] bf16
  float* OPl  = (float*)(OPo + (size_t)NTOT * KSPLIT * 64);

  k_ln_qkv<<<dim3(72, 3), 256, 0, stream>>>(x, ln1w, ln1b, qw, qb, kw, kb, vw, vb, Qg, Kg, Vg);
  k_attn_part<<<dim3(72, KSPLIT), 256, 0, stream>>>(Qg, Kg, Vg, OPo, OPl);
  k_attn_merge<<<dim3(72), 256, 0, stream>>>(OPo, OPl, ATT);
  k_res_ln2_proj<<<dim3(72, 4), 256, 0, stream>>>(x, ATT, ln2w, ln2b, piw, Hbuf);
  k_fft<<<dim3(72), 256, 0, stream>>>(Hbuf, fftw);
  k_dw_out<<<dim3(72, 2), 256, 0, stream>>>(Hbuf, dww, poww, x, ATT, (float*)d_out);
}

// Round 8
// 551.234 us; speedup vs baseline: 2.5492x; 2.5492x over previous
//
#include <hip/hip_runtime.h>
#include <hip/hip_bf16.h>
#include <math.h>

#define CH 64
#define NPOS 9216   // 96*96
#define NTOT 18432  // 2*9216

typedef short bf16x8 __attribute__((ext_vector_type(8)));
typedef float f32x4 __attribute__((ext_vector_type(4)));
typedef int   i32x4 __attribute__((ext_vector_type(4)));

__device__ __forceinline__ short f2bf(float f) {
  unsigned int u = __builtin_bit_cast(unsigned int, f);
  unsigned int r = (u + 0x7fffu + ((u >> 16) & 1u)) >> 16;  // RNE
  return (short)r;
}
__device__ __forceinline__ float gelu_exact(float x) {
  return 0.5f * x * (1.f + erff(x * 0.70710678118654752440f));
}

// Verified facts (R7 pass): inputs fp32, OUTPUT FP32, layout plain NCHW.
// R7 baseline 1405 us, k_attn_part (VALU) = 1298 us. This round: MFMA flash attn.

// ---------------- Kernel A: LN1 + QKV projection ----------------
// grid (72, 3) x 256. Writes Q/K/V bf16 in [b*N+n][c] layout.
__global__ __launch_bounds__(256) void k_ln_qkv(
    const float* __restrict__ x, const float* __restrict__ ln1w, const float* __restrict__ ln1b,
    const float* __restrict__ qw, const float* __restrict__ qb,
    const float* __restrict__ kw, const float* __restrict__ kb,
    const float* __restrict__ vw, const float* __restrict__ vb,
    short* __restrict__ Qg, short* __restrict__ Kg, short* __restrict__ Vg) {
  __shared__ float Wm[4096];
  __shared__ float bias[64], lw[64], lb[64];
  int mat = blockIdx.y;
  const float* wsrc = (mat == 0) ? qw : (mat == 1) ? kw : vw;
  const float* bsrc = (mat == 0) ? qb : (mat == 1) ? kb : vb;
  for (int i = threadIdx.x; i < 4096; i += 256) Wm[i] = wsrc[i];
  if (threadIdx.x < 64) {
    bias[threadIdx.x] = bsrc[threadIdx.x];
    lw[threadIdx.x] = ln1w[threadIdx.x];
    lb[threadIdx.x] = ln1b[threadIdx.x];
  }
  __syncthreads();
  int idx = blockIdx.x * 256 + threadIdx.x;
  int b = idx / NPOS, n = idx % NPOS;
  const float* xb = x + (size_t)b * CH * NPOS + n;
  float xr[64];
  float mu = 0.f;
#pragma unroll
  for (int c = 0; c < 64; ++c) { float v = xb[c * NPOS]; xr[c] = v; mu += v; }
  mu *= (1.f / 64.f);
  float var = 0.f;
#pragma unroll
  for (int c = 0; c < 64; ++c) { float d = xr[c] - mu; var += d * d; }
  float rstd = rsqrtf(var * (1.f / 64.f) + 1e-5f);
#pragma unroll
  for (int c = 0; c < 64; ++c) xr[c] = (xr[c] - mu) * rstd * lw[c] + lb[c];
  short* outp = ((mat == 0) ? Qg : (mat == 1) ? Kg : Vg) + (size_t)idx * 64;
  for (int o = 0; o < 64; ++o) {
    float acc = bias[o];
    const float* wrow = &Wm[o * 64];
#pragma unroll
    for (int c = 0; c < 64; ++c) acc += wrow[c] * xr[c];
    outp[o] = f2bf(acc);
  }
}

// ---------------- Kernel B: MFMA flash attention ----------------
// grid (144, 2) x 256. 64 queries/block, 16/wave. Unscaled softmax(Q K^T) V.
// LDS row stride 72 shorts (144 B): 16B-aligned, 2-way bank alias only (free, m136).
#define LDP 72
__global__ __launch_bounds__(256) void k_attn(
    const short* __restrict__ Qg, const short* __restrict__ Kg, const short* __restrict__ Vg,
    float* __restrict__ ATT) {
  __shared__ __align__(16) short Kt[64 * LDP];   // [key][dim]
  __shared__ __align__(16) short Vt[64 * LDP];   // [dim][key]
  __shared__ __align__(16) short Pl[4 * 16 * LDP];  // per-wave 16x64
  int b = blockIdx.y;
  int n0 = blockIdx.x * 64;
  int tid = threadIdx.x;
  int w = tid >> 6, lane = tid & 63;
  int L = lane & 15, quad = lane >> 4;

  const short* qbase = Qg + ((size_t)(b * NPOS + n0 + w * 16 + L)) * 64;
  bf16x8 qa0 = *(const bf16x8*)(qbase + quad * 8);
  bf16x8 qa1 = *(const bf16x8*)(qbase + 32 + quad * 8);

  f32x4 o[4];
  o[0] = (f32x4){0.f, 0.f, 0.f, 0.f}; o[1] = o[0]; o[2] = o[0]; o[3] = o[0];
  float m[4] = {-1e30f, -1e30f, -1e30f, -1e30f};
  float l[4] = {0.f, 0.f, 0.f, 0.f};

  for (int kt = 0; kt < 144; ++kt) {
    __syncthreads();
    // --- stage K tile: Kt[key][dim] ---
    {
      const i32x4* src = (const i32x4*)(Kg + ((size_t)(b * NPOS + kt * 64)) * 64);
      i32x4* dst = (i32x4*)Kt;
#pragma unroll
      for (int it = 0; it < 2; ++it) {
        int f = tid + it * 256;
        int key = f >> 3, c = f & 7;
        dst[key * 9 + c] = src[f];   // 9 chunks/row (8 data + 1 pad)
      }
      // --- stage V transposed: Vt[dim][key] ---
      int key = tid & 63, dg = tid >> 6;
      const short* vsrc = Vg + ((size_t)(b * NPOS + kt * 64 + key)) * 64 + dg * 16;
      bf16x8 va = *(const bf16x8*)(vsrc);
      bf16x8 vb2 = *(const bf16x8*)(vsrc + 8);
#pragma unroll
      for (int j = 0; j < 8; ++j) Vt[(dg * 16 + j) * LDP + key] = va[j];
#pragma unroll
      for (int j = 0; j < 8; ++j) Vt[(dg * 16 + 8 + j) * LDP + key] = vb2[j];
    }
    __syncthreads();

    // --- S = Q K^T (16 rows x 64 keys per wave) ---
    const i32x4* kt4 = (const i32x4*)Kt;
    f32x4 s[4];
#pragma unroll
    for (int cb = 0; cb < 4; ++cb) {
      int row = cb * 16 + L;
      bf16x8 kf0 = __builtin_bit_cast(bf16x8, kt4[row * 9 + quad]);
      bf16x8 kf1 = __builtin_bit_cast(bf16x8, kt4[row * 9 + 4 + quad]);
      f32x4 acc = {0.f, 0.f, 0.f, 0.f};
      acc = __builtin_amdgcn_mfma_f32_16x16x32_bf16(qa0, kf0, acc, 0, 0, 0);
      acc = __builtin_amdgcn_mfma_f32_16x16x32_bf16(qa1, kf1, acc, 0, 0, 0);
      s[cb] = acc;
    }

    // --- online softmax (rows = quad*4+i, cols = cb*16+L over 16 lanes) ---
    float mx[4];
#pragma unroll
    for (int i = 0; i < 4; ++i)
      mx[i] = fmaxf(fmaxf(s[0][i], s[1][i]), fmaxf(s[2][i], s[3][i]));
#pragma unroll
    for (int off = 1; off < 16; off <<= 1) {
#pragma unroll
      for (int i = 0; i < 4; ++i) mx[i] = fmaxf(mx[i], __shfl_xor(mx[i], off));
    }
    float mn[4], alpha[4], rs[4];
#pragma unroll
    for (int i = 0; i < 4; ++i) {
      mn[i] = fmaxf(m[i], mx[i]);
      alpha[i] = __expf(m[i] - mn[i]);
      rs[i] = 0.f;
    }
    f32x4 p[4];
#pragma unroll
    for (int cb = 0; cb < 4; ++cb)
#pragma unroll
      for (int i = 0; i < 4; ++i) {
        float e = __expf(s[cb][i] - mn[i]);
        p[cb][i] = e;
        rs[i] += e;
      }
#pragma unroll
    for (int off = 1; off < 16; off <<= 1) {
#pragma unroll
      for (int i = 0; i < 4; ++i) rs[i] += __shfl_xor(rs[i], off);
    }
#pragma unroll
    for (int i = 0; i < 4; ++i) { l[i] = l[i] * alpha[i] + rs[i]; m[i] = mn[i]; }
    f32x4 av = {alpha[0], alpha[1], alpha[2], alpha[3]};
#pragma unroll
    for (int nb = 0; nb < 4; ++nb) o[nb] *= av;

    // --- P: C-layout -> LDS -> A-layout ---
    short* pwb = Pl + w * 16 * LDP;
#pragma unroll
    for (int cb = 0; cb < 4; ++cb)
#pragma unroll
      for (int i = 0; i < 4; ++i) {
        int row = quad * 4 + i, col = cb * 16 + L;
        pwb[row * LDP + col] = f2bf(p[cb][i]);
      }
    __syncthreads();   // orders short P-writes before b128 P-reads
    const i32x4* p4 = (const i32x4*)pwb;
    bf16x8 pa0 = __builtin_bit_cast(bf16x8, p4[L * 9 + quad]);
    bf16x8 pa1 = __builtin_bit_cast(bf16x8, p4[L * 9 + 4 + quad]);

    // --- O += P V ---
    const i32x4* vt4 = (const i32x4*)Vt;
#pragma unroll
    for (int nb = 0; nb < 4; ++nb) {
      int d = nb * 16 + L;
      bf16x8 vf0 = __builtin_bit_cast(bf16x8, vt4[d * 9 + quad]);
      bf16x8 vf1 = __builtin_bit_cast(bf16x8, vt4[d * 9 + 4 + quad]);
      o[nb] = __builtin_amdgcn_mfma_f32_16x16x32_bf16(pa0, vf0, o[nb], 0, 0, 0);
      o[nb] = __builtin_amdgcn_mfma_f32_16x16x32_bf16(pa1, vf1, o[nb], 0, 0, 0);
    }
  }

  float inv[4];
#pragma unroll
  for (int i = 0; i < 4; ++i) inv[i] = 1.f / l[i];
#pragma unroll
  for (int nb = 0; nb < 4; ++nb)
#pragma unroll
    for (int i = 0; i < 4; ++i) {
      size_t ridx = (size_t)(b * NPOS + n0 + w * 16 + quad * 4 + i) * 64 + nb * 16 + L;
      ATT[ridx] = o[nb][i] * inv[i];
    }
}

// ---------------- Kernel C: residual + LN2 + proj_in ----------------
__global__ __launch_bounds__(256) void k_res_ln2_proj(
    const float* __restrict__ x, const float* __restrict__ ATT,
    const float* __restrict__ ln2w, const float* __restrict__ ln2b,
    const float* __restrict__ piw,
    float* __restrict__ Hbuf) {
  __shared__ float Wm[1024];
  __shared__ float lw[64], lb[64];
  int part = blockIdx.y;
  for (int i = threadIdx.x; i < 1024; i += 256) Wm[i] = piw[part * 1024 + i];
  if (threadIdx.x < 64) { lw[threadIdx.x] = ln2w[threadIdx.x]; lb[threadIdx.x] = ln2b[threadIdx.x]; }
  __syncthreads();
  int idx = blockIdx.x * 256 + threadIdx.x;
  int b = idx / NPOS, n = idx % NPOS;
  const float* xb = x + (size_t)b * CH * NPOS + n;
  const f32x4* att = (const f32x4*)(ATT + (size_t)idx * 64);
  float xr[64];
  float mu = 0.f;
#pragma unroll
  for (int c4 = 0; c4 < 16; ++c4) {
    f32x4 a = att[c4];
#pragma unroll
    for (int j = 0; j < 4; ++j) {
      int c = c4 * 4 + j;
      float v = xb[c * NPOS] + a[j];
      xr[c] = v;
      mu += v;
    }
  }
  mu *= (1.f / 64.f);
  float var = 0.f;
#pragma unroll
  for (int c = 0; c < 64; ++c) { float d = xr[c] - mu; var += d * d; }
  float rstd = rsqrtf(var * (1.f / 64.f) + 1e-5f);
#pragma unroll
  for (int c = 0; c < 64; ++c) xr[c] = (xr[c] - mu) * rstd * lw[c] + lb[c];
  float* hb = Hbuf + (size_t)b * CH * NPOS + (size_t)part * 16 * NPOS + n;
  for (int oo = 0; oo < 16; ++oo) {
    float acc = 0.f;
#pragma unroll
    for (int c = 0; c < 64; ++c) acc += Wm[oo * 64 + c] * xr[c];
    hb[oo * NPOS] = acc;
  }
}

// ---------------- Kernel D: per-patch spectral filter ----------------
__global__ __launch_bounds__(256) void k_fft(float* __restrict__ Hbuf, const float* __restrict__ fftw) {
  int idx = blockIdx.x * 256 + threadIdx.x;
  int c = idx & 63;
  int patch = idx >> 6;
  int wb = patch % 12;
  int t2 = patch / 12;
  int hb = t2 % 12;
  int b = t2 / 12;
  float* base = Hbuf + (size_t)(b * CH + c) * NPOS + (hb * 8) * 96 + wb * 8;
  const float r = 0.70710678118654752440f;
  const float CO[8] = {1.f, r, 0.f, -r, -1.f, -r, 0.f, r};
  const float SI[8] = {0.f, r, 1.f, r, 0.f, -r, -1.f, -r};
  float Ar[8][5], Ai[8][5];
#pragma unroll
  for (int p = 0; p < 8; ++p) {
    f32x4 ra = *(const f32x4*)(base + p * 96);
    f32x4 rb = *(const f32x4*)(base + p * 96 + 4);
    float row[8] = {ra[0], ra[1], ra[2], ra[3], rb[0], rb[1], rb[2], rb[3]};
#pragma unroll
    for (int v = 0; v < 5; ++v) {
      float sr = 0.f, si = 0.f;
#pragma unroll
      for (int q = 0; q < 8; ++q) {
        int k = (q * v) & 7;
        sr += row[q] * CO[k];
        si -= row[q] * SI[k];
      }
      Ar[p][v] = sr;
      Ai[p][v] = si;
    }
  }
  const float* wp = fftw + c * 40;
#pragma unroll
  for (int v = 0; v < 5; ++v) {
    float Br[8], Bi[8];
#pragma unroll
    for (int u = 0; u < 8; ++u) {
      float cr = 0.f, ci = 0.f;
#pragma unroll
      for (int p = 0; p < 8; ++p) {
        int k = (p * u) & 7;
        float cc = CO[k], ss = SI[k];
        cr += Ar[p][v] * cc + Ai[p][v] * ss;
        ci += Ai[p][v] * cc - Ar[p][v] * ss;
      }
      float wv = wp[u * 5 + v];
      Br[u] = cr * wv;
      Bi[u] = ci * wv;
    }
#pragma unroll
    for (int p = 0; p < 8; ++p) {
      float yr = 0.f, yi = 0.f;
#pragma unroll
      for (int u = 0; u < 8; ++u) {
        int k = (p * u) & 7;
        float cc = CO[k], ss = SI[k];
        yr += Br[u] * cc - Bi[u] * ss;
        yi += Bi[u] * cc + Br[u] * ss;
      }
      Ar[p][v] = yr * 0.125f;
      Ai[p][v] = yi * 0.125f;
    }
  }
#pragma unroll
  for (int p = 0; p < 8; ++p) {
    float outv[8];
#pragma unroll
    for (int q = 0; q < 8; ++q) {
      float acc = Ar[p][0] + ((q & 1) ? -Ar[p][4] : Ar[p][4]);
#pragma unroll
      for (int v = 1; v < 4; ++v) {
        int k = (q * v) & 7;
        acc += 2.f * (Ar[p][v] * CO[k] - Ai[p][v] * SI[k]);
      }
      outv[q] = acc * 0.125f;
    }
    f32x4 wa = {outv[0], outv[1], outv[2], outv[3]};
    f32x4 wb2 = {outv[4], outv[5], outv[6], outv[7]};
    *(f32x4*)(base + p * 96) = wa;
    *(f32x4*)(base + p * 96 + 4) = wb2;
  }
}

// ---------------- Kernel E: dwconv3x3 + gelu-gate + proj_out + residual ----------------
__global__ __launch_bounds__(256) void k_dw_out(
    const float* __restrict__ Hbuf, const float* __restrict__ dww,
    const float* __restrict__ poww, const float* __restrict__ x,
    const float* __restrict__ ATT, float* __restrict__ out) {
  __shared__ float dw[576];
  __shared__ float pw[1024];
  int half = blockIdx.y;
  for (int i = threadIdx.x; i < 576; i += 256) dw[i] = dww[i];
  for (int i = threadIdx.x; i < 1024; i += 256) pw[i] = poww[half * 1024 + i];
  __syncthreads();
  int idx = blockIdx.x * 256 + threadIdx.x;
  int b = idx / NPOS, n = idx % NPOS;
  int y = n / 96, xx = n % 96;
  const float* hb = Hbuf + (size_t)b * CH * NPOS;
  float g[32];
#pragma unroll
  for (int cc = 0; cc < 32; ++cc) {
    float d1 = 0.f, d2 = 0.f;
    for (int dy = -1; dy <= 1; ++dy) {
      int yy = y + dy;
      if (yy < 0 || yy >= 96) continue;
      for (int dx = -1; dx <= 1; ++dx) {
        int xv = xx + dx;
        if (xv < 0 || xv >= 96) continue;
        int ki = (dy + 1) * 3 + (dx + 1);
        d1 += hb[(size_t)cc * NPOS + yy * 96 + xv] * dw[cc * 9 + ki];
        d2 += hb[(size_t)(cc + 32) * NPOS + yy * 96 + xv] * dw[(cc + 32) * 9 + ki];
      }
    }
    g[cc] = gelu_exact(d1) * d2;
  }
  const float* xr = x + (size_t)b * CH * NPOS + (size_t)half * 32 * NPOS + n;
  const float* att = ATT + (size_t)idx * 64 + half * 32;
  float* ob = out + (size_t)b * CH * NPOS + (size_t)half * 32 * NPOS + n;
  for (int oo = 0; oo < 32; ++oo) {
    float acc = xr[oo * NPOS] + att[oo];
#pragma unroll
    for (int cg = 0; cg < 32; ++cg) acc += pw[oo * 32 + cg] * g[cg];
    ob[oo * NPOS] = acc;
  }
}

extern "C" void kernel_launch(void* const* d_in, const int* in_sizes, int n_in,
                              void* d_out, int out_size, void* d_ws, size_t ws_size,
                              hipStream_t stream) {
  const float* x    = (const float*)d_in[0];
  const float* ln1w = (const float*)d_in[1];
  const float* ln1b = (const float*)d_in[2];
  const float* ln2w = (const float*)d_in[3];
  const float* ln2b = (const float*)d_in[4];
  const float* qw   = (const float*)d_in[5];
  const float* qb   = (const float*)d_in[6];
  const float* kw   = (const float*)d_in[7];
  const float* kb   = (const float*)d_in[8];
  const float* vw   = (const float*)d_in[9];
  const float* vb   = (const float*)d_in[10];
  const float* fftw = (const float*)d_in[11];
  const float* piw  = (const float*)d_in[12];
  const float* dww  = (const float*)d_in[13];
  const float* poww = (const float*)d_in[14];

  short* Qg = (short*)d_ws;                          // [NTOT][64] bf16
  short* Kg = Qg + (size_t)NTOT * 64;
  short* Vg = Kg + (size_t)NTOT * 64;
  float* ATT  = (float*)(Vg + (size_t)NTOT * 64);    // [NTOT][64] f32
  float* Hbuf = ATT + (size_t)NTOT * 64;             // [b][c][n] f32

  k_ln_qkv<<<dim3(72, 3), 256, 0, stream>>>(x, ln1w, ln1b, qw, qb, kw, kb, vw, vb, Qg, Kg, Vg);
  k_attn<<<dim3(144, 2), 256, 0, stream>>>(Qg, Kg, Vg, ATT);
  k_res_ln2_proj<<<dim3(72, 4), 256, 0, stream>>>(x, ATT, ln2w, ln2b, piw, Hbuf);
  k_fft<<<dim3(72), 256, 0, stream>>>(Hbuf, fftw);
  k_dw_out<<<dim3(72, 2), 256, 0, stream>>>(Hbuf, dww, poww, x, ATT, (float*)d_out);
}

// Round 9
// 348.121 us; speedup vs baseline: 4.0365x; 1.5835x over previous
//
#include <hip/hip_runtime.h>
#include <hip/hip_bf16.h>
#include <math.h>

#define CH 64
#define NPOS 9216   // 96*96
#define NTOT 18432  // 2*9216
#define NSPLIT 4
#define TILES_PER_SPLIT 36   // 144/4

typedef short bf16x8 __attribute__((ext_vector_type(8)));
typedef float f32x4 __attribute__((ext_vector_type(4)));
typedef int   i32x4 __attribute__((ext_vector_type(4)));

__device__ __forceinline__ short f2bf(float f) {
  unsigned int u = __builtin_bit_cast(unsigned int, f);
  unsigned int r = (u + 0x7fffu + ((u >> 16) & 1u)) >> 16;  // RNE
  return (short)r;
}
__device__ __forceinline__ float gelu_exact(float x) {
  return 0.5f * x * (1.f + erff(x * 0.70710678118654752440f));
}

// Verified: inputs fp32, output fp32, plain NCHW. R8: attn latency-bound at
// 288 blocks (~1.1/CU), 3 barriers/iter. R9: K-split x4, no-max softmax,
// deferred l-reduce, 2 barriers/iter.

// ---------------- Kernel A: LN1 + QKV projection ----------------
// grid (72, 3) x 256. Writes Q/K/V bf16 in [b*N+n][c] layout, vectorized stores.
__global__ __launch_bounds__(256) void k_ln_qkv(
    const float* __restrict__ x, const float* __restrict__ ln1w, const float* __restrict__ ln1b,
    const float* __restrict__ qw, const float* __restrict__ qb,
    const float* __restrict__ kw, const float* __restrict__ kb,
    const float* __restrict__ vw, const float* __restrict__ vb,
    short* __restrict__ Qg, short* __restrict__ Kg, short* __restrict__ Vg) {
  __shared__ float Wm[4096];
  __shared__ float bias[64], lw[64], lb[64];
  int mat = blockIdx.y;
  const float* wsrc = (mat == 0) ? qw : (mat == 1) ? kw : vw;
  const float* bsrc = (mat == 0) ? qb : (mat == 1) ? kb : vb;
  for (int i = threadIdx.x; i < 4096; i += 256) Wm[i] = wsrc[i];
  if (threadIdx.x < 64) {
    bias[threadIdx.x] = bsrc[threadIdx.x];
    lw[threadIdx.x] = ln1w[threadIdx.x];
    lb[threadIdx.x] = ln1b[threadIdx.x];
  }
  __syncthreads();
  int idx = blockIdx.x * 256 + threadIdx.x;
  int b = idx / NPOS, n = idx % NPOS;
  const float* xb = x + (size_t)b * CH * NPOS + n;
  float xr[64];
  float mu = 0.f;
#pragma unroll
  for (int c = 0; c < 64; ++c) { float v = xb[c * NPOS]; xr[c] = v; mu += v; }
  mu *= (1.f / 64.f);
  float var = 0.f;
#pragma unroll
  for (int c = 0; c < 64; ++c) { float d = xr[c] - mu; var += d * d; }
  float rstd = rsqrtf(var * (1.f / 64.f) + 1e-5f);
#pragma unroll
  for (int c = 0; c < 64; ++c) xr[c] = (xr[c] - mu) * rstd * lw[c] + lb[c];
  short* outp = ((mat == 0) ? Qg : (mat == 1) ? Kg : Vg) + (size_t)idx * 64;
  for (int o2 = 0; o2 < 8; ++o2) {
    bf16x8 v8;
#pragma unroll
    for (int j = 0; j < 8; ++j) {
      int o = o2 * 8 + j;
      float acc = bias[o];
      const float* wrow = &Wm[o * 64];
#pragma unroll
      for (int c = 0; c < 64; ++c) acc += wrow[c] * xr[c];
      v8[j] = f2bf(acc);
    }
    *(bf16x8*)(outp + o2 * 8) = v8;
  }
}

// ---------------- Kernel B: MFMA flash attention, K-split ----------------
// grid (144, 2, NSPLIT) x 256. 64 queries/block, 16/wave.
// No max-subtraction (scores bounded; R7 precedent). Partials: Po (f32 64/q), Pl (f32 1/q).
#define LDP 72
__global__ __launch_bounds__(256) void k_attn(
    const short* __restrict__ Qg, const short* __restrict__ Kg, const short* __restrict__ Vg,
    float* __restrict__ Po, float* __restrict__ Pl) {
  __shared__ __align__(16) short Kt[64 * LDP];   // [key][dim]
  __shared__ __align__(16) short Vt[64 * LDP];   // [dim][key]
  __shared__ __align__(16) short Ps[4 * 16 * LDP];  // per-wave 16x64
  int b = blockIdx.y;
  int n0 = blockIdx.x * 64;
  int ks = blockIdx.z;
  int tid = threadIdx.x;
  int w = tid >> 6, lane = tid & 63;
  int L = lane & 15, quad = lane >> 4;

  const short* qbase = Qg + ((size_t)(b * NPOS + n0 + w * 16 + L)) * 64;
  bf16x8 qa0 = *(const bf16x8*)(qbase + quad * 8);
  bf16x8 qa1 = *(const bf16x8*)(qbase + 32 + quad * 8);

  f32x4 o[4];
  o[0] = (f32x4){0.f, 0.f, 0.f, 0.f}; o[1] = o[0]; o[2] = o[0]; o[3] = o[0];
  float rl[4] = {0.f, 0.f, 0.f, 0.f};   // per-lane partial row sums

  for (int t = 0; t < TILES_PER_SPLIT; ++t) {
    int kt = ks * TILES_PER_SPLIT + t;
    __syncthreads();
    // --- stage K tile: Kt[key][dim] ---
    {
      const i32x4* src = (const i32x4*)(Kg + ((size_t)(b * NPOS + kt * 64)) * 64);
      i32x4* dst = (i32x4*)Kt;
#pragma unroll
      for (int it = 0; it < 2; ++it) {
        int f = tid + it * 256;
        int key = f >> 3, c = f & 7;
        dst[key * 9 + c] = src[f];
      }
      // --- stage V transposed: Vt[dim][key] ---
      int key = tid & 63, dg = tid >> 6;
      const short* vsrc = Vg + ((size_t)(b * NPOS + kt * 64 + key)) * 64 + dg * 16;
      bf16x8 va = *(const bf16x8*)(vsrc);
      bf16x8 vb2 = *(const bf16x8*)(vsrc + 8);
#pragma unroll
      for (int j = 0; j < 8; ++j) Vt[(dg * 16 + j) * LDP + key] = va[j];
#pragma unroll
      for (int j = 0; j < 8; ++j) Vt[(dg * 16 + 8 + j) * LDP + key] = vb2[j];
    }
    __syncthreads();

    // --- S = Q K^T (16 rows x 64 keys per wave) ---
    const i32x4* kt4 = (const i32x4*)Kt;
    f32x4 s[4];
#pragma unroll
    for (int cb = 0; cb < 4; ++cb) {
      int row = cb * 16 + L;
      bf16x8 kf0 = __builtin_bit_cast(bf16x8, kt4[row * 9 + quad]);
      bf16x8 kf1 = __builtin_bit_cast(bf16x8, kt4[row * 9 + 4 + quad]);
      f32x4 acc = {0.f, 0.f, 0.f, 0.f};
      acc = __builtin_amdgcn_mfma_f32_16x16x32_bf16(qa0, kf0, acc, 0, 0, 0);
      acc = __builtin_amdgcn_mfma_f32_16x16x32_bf16(qa1, kf1, acc, 0, 0, 0);
      s[cb] = acc;
    }

    // --- p = e^s (no max subtraction), accumulate per-lane row sums ---
    f32x4 p[4];
#pragma unroll
    for (int cb = 0; cb < 4; ++cb)
#pragma unroll
      for (int i = 0; i < 4; ++i) {
        float e = __expf(s[cb][i]);
        p[cb][i] = e;
        rl[i] += e;
      }

    // --- P: C-layout -> per-wave LDS -> A-layout (same-wave: fence, no barrier) ---
    short* pwb = Ps + w * 16 * LDP;
#pragma unroll
    for (int cb = 0; cb < 4; ++cb)
#pragma unroll
      for (int i = 0; i < 4; ++i) {
        int row = quad * 4 + i, col = cb * 16 + L;
        pwb[row * LDP + col] = f2bf(p[cb][i]);
      }
    __asm__ volatile("s_waitcnt lgkmcnt(0)" ::: "memory");
    const i32x4* p4 = (const i32x4*)pwb;
    bf16x8 pa0 = __builtin_bit_cast(bf16x8, p4[L * 9 + quad]);
    bf16x8 pa1 = __builtin_bit_cast(bf16x8, p4[L * 9 + 4 + quad]);

    // --- O += P V ---
    const i32x4* vt4 = (const i32x4*)Vt;
#pragma unroll
    for (int nb = 0; nb < 4; ++nb) {
      int d = nb * 16 + L;
      bf16x8 vf0 = __builtin_bit_cast(bf16x8, vt4[d * 9 + quad]);
      bf16x8 vf1 = __builtin_bit_cast(bf16x8, vt4[d * 9 + 4 + quad]);
      o[nb] = __builtin_amdgcn_mfma_f32_16x16x32_bf16(pa0, vf0, o[nb], 0, 0, 0);
      o[nb] = __builtin_amdgcn_mfma_f32_16x16x32_bf16(pa1, vf1, o[nb], 0, 0, 0);
    }
  }

  // --- reduce l across 16 column-lanes (once) ---
#pragma unroll
  for (int off = 1; off < 16; off <<= 1) {
#pragma unroll
    for (int i = 0; i < 4; ++i) rl[i] += __shfl_xor(rl[i], off);
  }

  float* pb = Po + ((size_t)ks * NTOT + b * NPOS + n0 + w * 16) * 64;
#pragma unroll
  for (int nb = 0; nb < 4; ++nb)
#pragma unroll
    for (int i = 0; i < 4; ++i)
      pb[(quad * 4 + i) * 64 + nb * 16 + L] = o[nb][i];
  if (L == 0) {
#pragma unroll
    for (int i = 0; i < 4; ++i)
      Pl[(size_t)ks * NTOT + b * NPOS + n0 + w * 16 + quad * 4 + i] = rl[i];
  }
}

// ---------------- Kernel C: merge + residual + LN2 + proj_in ----------------
// grid (72, 4) x 256. attn = (sum_s Po) / (sum_s Pl), xr = x + attn.
__global__ __launch_bounds__(256) void k_res_ln2_proj(
    const float* __restrict__ x, const float* __restrict__ Po, const float* __restrict__ Pl,
    const float* __restrict__ ln2w, const float* __restrict__ ln2b,
    const float* __restrict__ piw,
    float* __restrict__ Hbuf) {
  __shared__ float Wm[1024];
  __shared__ float lw[64], lb[64];
  int part = blockIdx.y;
  for (int i = threadIdx.x; i < 1024; i += 256) Wm[i] = piw[part * 1024 + i];
  if (threadIdx.x < 64) { lw[threadIdx.x] = ln2w[threadIdx.x]; lb[threadIdx.x] = ln2b[threadIdx.x]; }
  __syncthreads();
  int idx = blockIdx.x * 256 + threadIdx.x;
  int b = idx / NPOS, n = idx % NPOS;
  const float* xb = x + (size_t)b * CH * NPOS + n;
  float lsum = 0.f;
#pragma unroll
  for (int s = 0; s < NSPLIT; ++s) lsum += Pl[(size_t)s * NTOT + idx];
  float inv = 1.f / lsum;
  float xr[64];
  float mu = 0.f;
#pragma unroll
  for (int c4 = 0; c4 < 16; ++c4) {
    f32x4 a = (f32x4){0.f, 0.f, 0.f, 0.f};
#pragma unroll
    for (int s = 0; s < NSPLIT; ++s)
      a += *(const f32x4*)(Po + ((size_t)s * NTOT + idx) * 64 + c4 * 4);
#pragma unroll
    for (int j = 0; j < 4; ++j) {
      int c = c4 * 4 + j;
      float v = xb[c * NPOS] + a[j] * inv;
      xr[c] = v;
      mu += v;
    }
  }
  mu *= (1.f / 64.f);
  float var = 0.f;
#pragma unroll
  for (int c = 0; c < 64; ++c) { float d = xr[c] - mu; var += d * d; }
  float rstd = rsqrtf(var * (1.f / 64.f) + 1e-5f);
#pragma unroll
  for (int c = 0; c < 64; ++c) xr[c] = (xr[c] - mu) * rstd * lw[c] + lb[c];
  float* hb = Hbuf + (size_t)b * CH * NPOS + (size_t)part * 16 * NPOS + n;
  for (int oo = 0; oo < 16; ++oo) {
    float acc = 0.f;
#pragma unroll
    for (int c = 0; c < 64; ++c) acc += Wm[oo * 64 + c] * xr[c];
    hb[oo * NPOS] = acc;
  }
}

// ---------------- Kernel D: per-patch spectral filter ----------------
// grid (288) x 64. Decode wb fastest -> coalesced 384B spans per (hb,p).
__global__ __launch_bounds__(64) void k_fft(float* __restrict__ Hbuf, const float* __restrict__ fftw) {
  int idx = blockIdx.x * 64 + threadIdx.x;
  int wb = idx % 12;
  int t = idx / 12;
  int hb = t % 12;
  int t2 = t / 12;
  int c = t2 % 64;
  int b = t2 / 64;
  float* base = Hbuf + (size_t)(b * CH + c) * NPOS + (hb * 8) * 96 + wb * 8;
  const float r = 0.70710678118654752440f;
  const float CO[8] = {1.f, r, 0.f, -r, -1.f, -r, 0.f, r};
  const float SI[8] = {0.f, r, 1.f, r, 0.f, -r, -1.f, -r};
  float Ar[8][5], Ai[8][5];
#pragma unroll
  for (int p = 0; p < 8; ++p) {
    f32x4 ra = *(const f32x4*)(base + p * 96);
    f32x4 rb = *(const f32x4*)(base + p * 96 + 4);
    float row[8] = {ra[0], ra[1], ra[2], ra[3], rb[0], rb[1], rb[2], rb[3]};
#pragma unroll
    for (int v = 0; v < 5; ++v) {
      float sr = 0.f, si = 0.f;
#pragma unroll
      for (int q = 0; q < 8; ++q) {
        int k = (q * v) & 7;
        sr += row[q] * CO[k];
        si -= row[q] * SI[k];
      }
      Ar[p][v] = sr;
      Ai[p][v] = si;
    }
  }
  const float* wp = fftw + c * 40;
#pragma unroll
  for (int v = 0; v < 5; ++v) {
    float Br[8], Bi[8];
#pragma unroll
    for (int u = 0; u < 8; ++u) {
      float cr = 0.f, ci = 0.f;
#pragma unroll
      for (int p = 0; p < 8; ++p) {
        int k = (p * u) & 7;
        float cc = CO[k], ss = SI[k];
        cr += Ar[p][v] * cc + Ai[p][v] * ss;
        ci += Ai[p][v] * cc - Ar[p][v] * ss;
      }
      float wv = wp[u * 5 + v];
      Br[u] = cr * wv;
      Bi[u] = ci * wv;
    }
#pragma unroll
    for (int p = 0; p < 8; ++p) {
      float yr = 0.f, yi = 0.f;
#pragma unroll
      for (int u = 0; u < 8; ++u) {
        int k = (p * u) & 7;
        float cc = CO[k], ss = SI[k];
        yr += Br[u] * cc - Bi[u] * ss;
        yi += Bi[u] * cc + Br[u] * ss;
      }
      Ar[p][v] = yr * 0.125f;
      Ai[p][v] = yi * 0.125f;
    }
  }
#pragma unroll
  for (int p = 0; p < 8; ++p) {
    float outv[8];
#pragma unroll
    for (int q = 0; q < 8; ++q) {
      float acc = Ar[p][0] + ((q & 1) ? -Ar[p][4] : Ar[p][4]);
#pragma unroll
      for (int v = 1; v < 4; ++v) {
        int k = (q * v) & 7;
        acc += 2.f * (Ar[p][v] * CO[k] - Ai[p][v] * SI[k]);
      }
      outv[q] = acc * 0.125f;
    }
    f32x4 wa = {outv[0], outv[1], outv[2], outv[3]};
    f32x4 wb2 = {outv[4], outv[5], outv[6], outv[7]};
    *(f32x4*)(base + p * 96) = wa;
    *(f32x4*)(base + p * 96 + 4) = wb2;
  }
}

// ---------------- Kernel E: dwconv3x3 + gelu-gate + proj_out + residual ----------------
// grid (72, 2) x 256. Residual merged from Po/Pl partials.
__global__ __launch_bounds__(256) void k_dw_out(
    const float* __restrict__ Hbuf, const float* __restrict__ dww,
    const float* __restrict__ poww, const float* __restrict__ x,
    const float* __restrict__ Po, const float* __restrict__ Pl,
    float* __restrict__ out) {
  __shared__ float dw[576];
  __shared__ float pw[1024];
  int half = blockIdx.y;
  for (int i = threadIdx.x; i < 576; i += 256) dw[i] = dww[i];
  for (int i = threadIdx.x; i < 1024; i += 256) pw[i] = poww[half * 1024 + i];
  __syncthreads();
  int idx = blockIdx.x * 256 + threadIdx.x;
  int b = idx / NPOS, n = idx % NPOS;
  int y = n / 96, xx = n % 96;
  const float* hb = Hbuf + (size_t)b * CH * NPOS;
  float g[32];
#pragma unroll
  for (int cc = 0; cc < 32; ++cc) {
    float d1 = 0.f, d2 = 0.f;
    for (int dy = -1; dy <= 1; ++dy) {
      int yy = y + dy;
      if (yy < 0 || yy >= 96) continue;
      for (int dx = -1; dx <= 1; ++dx) {
        int xv = xx + dx;
        if (xv < 0 || xv >= 96) continue;
        int ki = (dy + 1) * 3 + (dx + 1);
        d1 += hb[(size_t)cc * NPOS + yy * 96 + xv] * dw[cc * 9 + ki];
        d2 += hb[(size_t)(cc + 32) * NPOS + yy * 96 + xv] * dw[(cc + 32) * 9 + ki];
      }
    }
    g[cc] = gelu_exact(d1) * d2;
  }
  float lsum = 0.f;
#pragma unroll
  for (int s = 0; s < NSPLIT; ++s) lsum += Pl[(size_t)s * NTOT + idx];
  float inv = 1.f / lsum;
  f32x4 av[8];
#pragma unroll
  for (int c4 = 0; c4 < 8; ++c4) av[c4] = (f32x4){0.f, 0.f, 0.f, 0.f};
#pragma unroll
  for (int s = 0; s < NSPLIT; ++s) {
    const float* pp = Po + ((size_t)s * NTOT + idx) * 64 + half * 32;
#pragma unroll
    for (int c4 = 0; c4 < 8; ++c4) av[c4] += *(const f32x4*)(pp + c4 * 4);
  }
  const float* xr = x + (size_t)b * CH * NPOS + (size_t)half * 32 * NPOS + n;
  float* ob = out + (size_t)b * CH * NPOS + (size_t)half * 32 * NPOS + n;
  for (int oo = 0; oo < 32; ++oo) {
    float acc = xr[oo * NPOS] + av[oo >> 2][oo & 3] * inv;
#pragma unroll
    for (int cg = 0; cg < 32; ++cg) acc += pw[oo * 32 + cg] * g[cg];
    ob[oo * NPOS] = acc;
  }
}

extern "C" void kernel_launch(void* const* d_in, const int* in_sizes, int n_in,
                              void* d_out, int out_size, void* d_ws, size_t ws_size,
                              hipStream_t stream) {
  const float* x    = (const float*)d_in[0];
  const float* ln1w = (const float*)d_in[1];
  const float* ln1b = (const float*)d_in[2];
  const float* ln2w = (const float*)d_in[3];
  const float* ln2b = (const float*)d_in[4];
  const float* qw   = (const float*)d_in[5];
  const float* qb   = (const float*)d_in[6];
  const float* kw   = (const float*)d_in[7];
  const float* kb   = (const float*)d_in[8];
  const float* vw   = (const float*)d_in[9];
  const float* vb   = (const float*)d_in[10];
  const float* fftw = (const float*)d_in[11];
  const float* piw  = (const float*)d_in[12];
  const float* dww  = (const float*)d_in[13];
  const float* poww = (const float*)d_in[14];

  short* Qg = (short*)d_ws;                          // [NTOT][64] bf16 (2.36 MB)
  short* Kg = Qg + (size_t)NTOT * 64;
  short* Vg = Kg + (size_t)NTOT * 64;
  float* Po = (float*)(Vg + (size_t)NTOT * 64);      // [NSPLIT][NTOT][64] f32 (18.9 MB)
  float* Pl = Po + (size_t)NSPLIT * NTOT * 64;       // [NSPLIT][NTOT] f32 (0.3 MB)
  float* Hbuf = Pl + (size_t)NSPLIT * NTOT;          // [b][c][n] f32 (9.4 MB)

  k_ln_qkv<<<dim3(72, 3), 256, 0, stream>>>(x, ln1w, ln1b, qw, qb, kw, kb, vw, vb, Qg, Kg, Vg);
  k_attn<<<dim3(144, 2, NSPLIT), 256, 0, stream>>>(Qg, Kg, Vg, Po, Pl);
  k_res_ln2_proj<<<dim3(72, 4), 256, 0, stream>>>(x, Po, Pl, ln2w, ln2b, piw, Hbuf);
  k_fft<<<dim3(288), 64, 0, stream>>>(Hbuf, fftw);
  k_dw_out<<<dim3(72, 2), 256, 0, stream>>>(Hbuf, dww, poww, x, Po, Pl, (float*)d_out);
}

// Round 10
// 332.460 us; speedup vs baseline: 4.2267x; 1.0471x over previous
//
#include <hip/hip_runtime.h>
#include <hip/hip_bf16.h>
#include <math.h>

#define CH 64
#define NPOS 9216   // 96*96
#define NTOT 18432  // 2*9216
#define NSPLIT 4
#define TILES_PER_SPLIT 36   // 144/4
#define LOG2E 1.4426950408889634f

typedef short bf16x8 __attribute__((ext_vector_type(8)));
typedef short bf16x4 __attribute__((ext_vector_type(4)));
typedef float f32x4 __attribute__((ext_vector_type(4)));
typedef int   i32x4 __attribute__((ext_vector_type(4)));
typedef unsigned int u32;

__device__ __forceinline__ float bf2f(short s) {
  unsigned int u = ((unsigned int)(unsigned short)s) << 16;
  return __builtin_bit_cast(float, u);
}
__device__ __forceinline__ short f2bf(float f) {
  unsigned int u = __builtin_bit_cast(unsigned int, f);
  unsigned int r = (u + 0x7fffu + ((u >> 16) & 1u)) >> 16;  // RNE
  return (short)r;
}
__device__ __forceinline__ float gelu_exact(float x) {
  return 0.5f * x * (1.f + erff(x * 0.70710678118654752440f));
}

// Verified: inputs fp32, output fp32, plain NCHW. R9: attn LDS-bound (P LDS
// round-trip + no Q reuse). R10: S^T scheme -> P feeds PV MFMA from regs
// (16x16x16 D->B chaining), 32q/wave, K pre-scaled by log2e, Po^T bf16, X2 buffer.

// ---------------- Kernel A: LN1 + QKV projection ----------------
// grid (72, 3) x 256. K output pre-scaled by log2(e) for exp2-softmax.
__global__ __launch_bounds__(256) void k_ln_qkv(
    const float* __restrict__ x, const float* __restrict__ ln1w, const float* __restrict__ ln1b,
    const float* __restrict__ qw, const float* __restrict__ qb,
    const float* __restrict__ kw, const float* __restrict__ kb,
    const float* __restrict__ vw, const float* __restrict__ vb,
    short* __restrict__ Qg, short* __restrict__ Kg, short* __restrict__ Vg) {
  __shared__ float Wm[4096];
  __shared__ float bias[64], lw[64], lb[64];
  int mat = blockIdx.y;
  const float* wsrc = (mat == 0) ? qw : (mat == 1) ? kw : vw;
  const float* bsrc = (mat == 0) ? qb : (mat == 1) ? kb : vb;
  for (int i = threadIdx.x; i < 4096; i += 256) Wm[i] = wsrc[i];
  if (threadIdx.x < 64) {
    bias[threadIdx.x] = bsrc[threadIdx.x];
    lw[threadIdx.x] = ln1w[threadIdx.x];
    lb[threadIdx.x] = ln1b[threadIdx.x];
  }
  __syncthreads();
  int idx = blockIdx.x * 256 + threadIdx.x;
  int b = idx / NPOS, n = idx % NPOS;
  const float* xb = x + (size_t)b * CH * NPOS + n;
  float xr[64];
  float mu = 0.f;
#pragma unroll
  for (int c = 0; c < 64; ++c) { float v = xb[c * NPOS]; xr[c] = v; mu += v; }
  mu *= (1.f / 64.f);
  float var = 0.f;
#pragma unroll
  for (int c = 0; c < 64; ++c) { float d = xr[c] - mu; var += d * d; }
  float rstd = rsqrtf(var * (1.f / 64.f) + 1e-5f);
#pragma unroll
  for (int c = 0; c < 64; ++c) xr[c] = (xr[c] - mu) * rstd * lw[c] + lb[c];
  float kscale = (mat == 1) ? LOG2E : 1.f;
  short* outp = ((mat == 0) ? Qg : (mat == 1) ? Kg : Vg) + (size_t)idx * 64;
  for (int o2 = 0; o2 < 8; ++o2) {
    bf16x8 v8;
#pragma unroll
    for (int j = 0; j < 8; ++j) {
      int o = o2 * 8 + j;
      float acc = bias[o];
      const float* wrow = &Wm[o * 64];
#pragma unroll
      for (int c = 0; c < 64; ++c) acc += wrow[c] * xr[c];
      v8[j] = f2bf(acc * kscale);
    }
    *(bf16x8*)(outp + o2 * 8) = v8;
  }
}

// ---------------- Kernel B: MFMA flash attention, S^T scheme ----------------
// grid (72, 2, NSPLIT) x 256. 128 queries/block, 32/wave (2 q-tiles).
// S^T = K.Q^T (16x16x32); p=exp2(s) packed bf16 in regs feeds PV (16x16x16)
// as B operand directly (C/D layout == B layout, k=quad*4+i). O^T accum.
#define LDP 72
#if __has_builtin(__builtin_amdgcn_mfma_f32_16x16x16bf16_1k)
#define HAVE_MFMA16 1
#else
#define HAVE_MFMA16 0
#endif

__global__ __launch_bounds__(256) void k_attn(
    const short* __restrict__ Qg, const short* __restrict__ Kg, const short* __restrict__ Vg,
    short* __restrict__ PoT, float* __restrict__ Pl) {
  __shared__ __align__(16) short Kt[64 * LDP];   // [key][dim]
  __shared__ __align__(16) short Vt[64 * LDP];   // [dim][key]
#if !HAVE_MFMA16
  __shared__ __align__(16) short Ps[4 * 32 * LDP];  // fallback: per-wave P^T [q][key]
#endif
  int b = blockIdx.y;
  int n0 = blockIdx.x * 128;
  int ks = blockIdx.z;
  int tid = threadIdx.x;
  int w = tid >> 6, lane = tid & 63;
  int L = lane & 15, quad = lane >> 4;

  // Q fragments for 2 query-tiles (as B operand of 16x16x32: q=lane&15, ch=quad*8+j)
  bf16x8 qa[2][2];
#pragma unroll
  for (int qt = 0; qt < 2; ++qt) {
    const short* qb_ = Qg + ((size_t)(b * NPOS + n0 + w * 32 + qt * 16 + L)) * 64;
    qa[qt][0] = *(const bf16x8*)(qb_ + quad * 8);
    qa[qt][1] = *(const bf16x8*)(qb_ + 32 + quad * 8);
  }

  f32x4 o[2][4];  // O^T accum: [qt][dim-block], col=q=lane&15, row=dim=quad*4+i
#pragma unroll
  for (int qt = 0; qt < 2; ++qt)
#pragma unroll
    for (int nb = 0; nb < 4; ++nb) o[qt][nb] = (f32x4){0.f, 0.f, 0.f, 0.f};
  float rl[2] = {0.f, 0.f};

  for (int t = 0; t < TILES_PER_SPLIT; ++t) {
    int kt = ks * TILES_PER_SPLIT + t;
    __syncthreads();
    {
      // stage K tile: Kt[key][dim]
      const i32x4* src = (const i32x4*)(Kg + ((size_t)(b * NPOS + kt * 64)) * 64);
      i32x4* dst = (i32x4*)Kt;
#pragma unroll
      for (int it = 0; it < 2; ++it) {
        int f = tid + it * 256;
        int key = f >> 3, c = f & 7;
        dst[key * 9 + c] = src[f];
      }
      // stage V^T: Vt[dim][key], packed-pair b32 writes
      int k2 = tid & 31, dg = tid >> 5;  // key pair (2k2,2k2+1), dim group of 8
      const short* vs0 = Vg + ((size_t)(b * NPOS + kt * 64 + 2 * k2)) * 64 + dg * 8;
      bf16x8 v0 = *(const bf16x8*)vs0;
      bf16x8 v1 = *(const bf16x8*)(vs0 + 64);
      u32* vtw = (u32*)Vt;
      const u32* v0w = (const u32*)&v0;
      const u32* v1w = (const u32*)&v1;
#pragma unroll
      for (int j = 0; j < 8; ++j) {
        u32 pk = (j & 1) ? __builtin_amdgcn_perm(v1w[j >> 1], v0w[j >> 1], 0x07060302u)
                         : __builtin_amdgcn_perm(v1w[j >> 1], v0w[j >> 1], 0x05040100u);
        vtw[(dg * 8 + j) * 36 + k2] = pk;
      }
    }
    __syncthreads();

    const i32x4* kt4 = (const i32x4*)Kt;
#if HAVE_MFMA16
#pragma unroll
    for (int kti = 0; kti < 4; ++kti) {
      // S^T tile: A = K rows (key=lane&15 within tile), B = Q^T
      bf16x8 kf0 = __builtin_bit_cast(bf16x8, kt4[(kti * 16 + L) * 9 + quad]);
      bf16x8 kf1 = __builtin_bit_cast(bf16x8, kt4[(kti * 16 + L) * 9 + 4 + quad]);
      bf16x4 pp[2];
#pragma unroll
      for (int qt = 0; qt < 2; ++qt) {
        f32x4 st = {0.f, 0.f, 0.f, 0.f};
        st = __builtin_amdgcn_mfma_f32_16x16x32_bf16(kf0, qa[qt][0], st, 0, 0, 0);
        st = __builtin_amdgcn_mfma_f32_16x16x32_bf16(kf1, qa[qt][1], st, 0, 0, 0);
        float p0 = exp2f(st[0]), p1 = exp2f(st[1]), p2 = exp2f(st[2]), p3 = exp2f(st[3]);
        rl[qt] += (p0 + p1) + (p2 + p3);
        u32 lo = __builtin_amdgcn_perm(__builtin_bit_cast(u32, p1), __builtin_bit_cast(u32, p0), 0x07060302u);
        u32 hi = __builtin_amdgcn_perm(__builtin_bit_cast(u32, p3), __builtin_bit_cast(u32, p2), 0x07060302u);
        u32 pr[2] = {lo, hi};
        pp[qt] = __builtin_bit_cast(bf16x4, pr);
      }
      // PV: O^T += V^T . P^T  (A = V^T b64 frag, B = pp from regs)
#pragma unroll
      for (int nb = 0; nb < 4; ++nb) {
        bf16x4 va = *(const bf16x4*)(Vt + (nb * 16 + L) * LDP + kti * 16 + quad * 4);
#pragma unroll
        for (int qt = 0; qt < 2; ++qt)
          o[qt][nb] = __builtin_amdgcn_mfma_f32_16x16x16bf16_1k(va, pp[qt], o[qt][nb], 0, 0, 0);
      }
    }
#else
    // Fallback: packed-b64 P^T LDS round-trip, PV via 16x16x32
    short* psw = Ps + w * 32 * LDP;
#pragma unroll
    for (int kti = 0; kti < 4; ++kti) {
      bf16x8 kf0 = __builtin_bit_cast(bf16x8, kt4[(kti * 16 + L) * 9 + quad]);
      bf16x8 kf1 = __builtin_bit_cast(bf16x8, kt4[(kti * 16 + L) * 9 + 4 + quad]);
#pragma unroll
      for (int qt = 0; qt < 2; ++qt) {
        f32x4 st = {0.f, 0.f, 0.f, 0.f};
        st = __builtin_amdgcn_mfma_f32_16x16x32_bf16(kf0, qa[qt][0], st, 0, 0, 0);
        st = __builtin_amdgcn_mfma_f32_16x16x32_bf16(kf1, qa[qt][1], st, 0, 0, 0);
        float p0 = exp2f(st[0]), p1 = exp2f(st[1]), p2 = exp2f(st[2]), p3 = exp2f(st[3]);
        rl[qt] += (p0 + p1) + (p2 + p3);
        u32 lo = __builtin_amdgcn_perm(__builtin_bit_cast(u32, p1), __builtin_bit_cast(u32, p0), 0x07060302u);
        u32 hi = __builtin_amdgcn_perm(__builtin_bit_cast(u32, p3), __builtin_bit_cast(u32, p2), 0x07060302u);
        u32 pr[2] = {lo, hi};
        *(u32*)(psw + (qt * 16 + L) * LDP + kti * 16 + quad * 4) = pr[0];
        *(u32*)(psw + (qt * 16 + L) * LDP + kti * 16 + quad * 4 + 2) = pr[1];
      }
    }
    __asm__ volatile("s_waitcnt lgkmcnt(0)" ::: "memory");
#pragma unroll
    for (int kc = 0; kc < 2; ++kc) {
      bf16x8 pb[2];
#pragma unroll
      for (int qt = 0; qt < 2; ++qt)
        pb[qt] = *(const bf16x8*)(psw + (qt * 16 + L) * LDP + kc * 32 + quad * 8);
#pragma unroll
      for (int nb = 0; nb < 4; ++nb) {
        bf16x8 va = *(const bf16x8*)(Vt + (nb * 16 + L) * LDP + kc * 32 + quad * 8);
#pragma unroll
        for (int qt = 0; qt < 2; ++qt)
          o[qt][nb] = __builtin_amdgcn_mfma_f32_16x16x32_bf16(va, pb[qt], o[qt][nb], 0, 0, 0);
      }
    }
#endif
  }

  // reduce row-sums across quads (lanes with same L)
#pragma unroll
  for (int qt = 0; qt < 2; ++qt) {
    rl[qt] += __shfl_xor(rl[qt], 16);
    rl[qt] += __shfl_xor(rl[qt], 32);
  }

  // store O^T partials as bf16, coalesced (consecutive lanes = consecutive queries)
#pragma unroll
  for (int qt = 0; qt < 2; ++qt) {
    int qg = b * NPOS + n0 + w * 32 + qt * 16 + L;
#pragma unroll
    for (int nb = 0; nb < 4; ++nb)
#pragma unroll
      for (int i = 0; i < 4; ++i) {
        int d = nb * 16 + quad * 4 + i;
        PoT[((size_t)(ks * 64 + d)) * NTOT + qg] = f2bf(o[qt][nb][i]);
      }
    if (quad == 0) Pl[(size_t)ks * NTOT + qg] = rl[qt];
  }
}

// ---------------- Kernel C: merge + residual + LN2 + proj_in (+X2) ----------------
// grid (72, 2) x 256. part covers 32 proj output channels; part 0 writes X2.
__global__ __launch_bounds__(256) void k_res_ln2_proj(
    const float* __restrict__ x, const short* __restrict__ PoT, const float* __restrict__ Pl,
    const float* __restrict__ ln2w, const float* __restrict__ ln2b,
    const float* __restrict__ piw,
    float* __restrict__ X2, float* __restrict__ Hbuf) {
  __shared__ float Wm[2048];
  __shared__ float lw[64], lb[64];
  int part = blockIdx.y;
  for (int i = threadIdx.x; i < 2048; i += 256) Wm[i] = piw[part * 2048 + i];
  if (threadIdx.x < 64) { lw[threadIdx.x] = ln2w[threadIdx.x]; lb[threadIdx.x] = ln2b[threadIdx.x]; }
  __syncthreads();
  int idx = blockIdx.x * 256 + threadIdx.x;
  int b = idx / NPOS, n = idx % NPOS;
  const float* xb = x + (size_t)b * CH * NPOS + n;
  float lsum = 0.f;
#pragma unroll
  for (int s = 0; s < NSPLIT; ++s) lsum += Pl[(size_t)s * NTOT + idx];
  float inv = 1.f / lsum;
  float xr[64];
  float mu = 0.f;
#pragma unroll
  for (int c = 0; c < 64; ++c) {
    float a = 0.f;
#pragma unroll
    for (int s = 0; s < NSPLIT; ++s) a += bf2f(PoT[(size_t)(s * 64 + c) * NTOT + idx]);
    float v = xb[c * NPOS] + a * inv;
    xr[c] = v;
    mu += v;
  }
  if (part == 0) {
    float* xo = X2 + (size_t)b * CH * NPOS + n;
#pragma unroll
    for (int c = 0; c < 64; ++c) xo[c * NPOS] = xr[c];
  }
  mu *= (1.f / 64.f);
  float var = 0.f;
#pragma unroll
  for (int c = 0; c < 64; ++c) { float d = xr[c] - mu; var += d * d; }
  float rstd = rsqrtf(var * (1.f / 64.f) + 1e-5f);
#pragma unroll
  for (int c = 0; c < 64; ++c) xr[c] = (xr[c] - mu) * rstd * lw[c] + lb[c];
  float* hb = Hbuf + (size_t)b * CH * NPOS + (size_t)part * 32 * NPOS + n;
  for (int oo = 0; oo < 32; ++oo) {
    float acc = 0.f;
#pragma unroll
    for (int c = 0; c < 64; ++c) acc += Wm[oo * 64 + c] * xr[c];
    hb[oo * NPOS] = acc;
  }
}

// ---------------- Kernel D: per-patch spectral filter ----------------
// grid (288) x 64. wb fastest -> coalesced 384B spans.
__global__ __launch_bounds__(64) void k_fft(float* __restrict__ Hbuf, const float* __restrict__ fftw) {
  int idx = blockIdx.x * 64 + threadIdx.x;
  int wb = idx % 12;
  int t = idx / 12;
  int hb = t % 12;
  int t2 = t / 12;
  int c = t2 % 64;
  int b = t2 / 64;
  float* base = Hbuf + (size_t)(b * CH + c) * NPOS + (hb * 8) * 96 + wb * 8;
  const float r = 0.70710678118654752440f;
  const float CO[8] = {1.f, r, 0.f, -r, -1.f, -r, 0.f, r};
  const float SI[8] = {0.f, r, 1.f, r, 0.f, -r, -1.f, -r};
  float Ar[8][5], Ai[8][5];
#pragma unroll
  for (int p = 0; p < 8; ++p) {
    f32x4 ra = *(const f32x4*)(base + p * 96);
    f32x4 rb = *(const f32x4*)(base + p * 96 + 4);
    float row[8] = {ra[0], ra[1], ra[2], ra[3], rb[0], rb[1], rb[2], rb[3]};
#pragma unroll
    for (int v = 0; v < 5; ++v) {
      float sr = 0.f, si = 0.f;
#pragma unroll
      for (int q = 0; q < 8; ++q) {
        int k = (q * v) & 7;
        sr += row[q] * CO[k];
        si -= row[q] * SI[k];
      }
      Ar[p][v] = sr;
      Ai[p][v] = si;
    }
  }
  const float* wp = fftw + c * 40;
#pragma unroll
  for (int v = 0; v < 5; ++v) {
    float Br[8], Bi[8];
#pragma unroll
    for (int u = 0; u < 8; ++u) {
      float cr = 0.f, ci = 0.f;
#pragma unroll
      for (int p = 0; p < 8; ++p) {
        int k = (p * u) & 7;
        float cc = CO[k], ss = SI[k];
        cr += Ar[p][v] * cc + Ai[p][v] * ss;
        ci += Ai[p][v] * cc - Ar[p][v] * ss;
      }
      float wv = wp[u * 5 + v];
      Br[u] = cr * wv;
      Bi[u] = ci * wv;
    }
#pragma unroll
    for (int p = 0; p < 8; ++p) {
      float yr = 0.f, yi = 0.f;
#pragma unroll
      for (int u = 0; u < 8; ++u) {
        int k = (p * u) & 7;
        float cc = CO[k], ss = SI[k];
        yr += Br[u] * cc - Bi[u] * ss;
        yi += Bi[u] * cc + Br[u] * ss;
      }
      Ar[p][v] = yr * 0.125f;
      Ai[p][v] = yi * 0.125f;
    }
  }
#pragma unroll
  for (int p = 0; p < 8; ++p) {
    float outv[8];
#pragma unroll
    for (int q = 0; q < 8; ++q) {
      float acc = Ar[p][0] + ((q & 1) ? -Ar[p][4] : Ar[p][4]);
#pragma unroll
      for (int v = 1; v < 4; ++v) {
        int k = (q * v) & 7;
        acc += 2.f * (Ar[p][v] * CO[k] - Ai[p][v] * SI[k]);
      }
      outv[q] = acc * 0.125f;
    }
    f32x4 wa = {outv[0], outv[1], outv[2], outv[3]};
    f32x4 wb2 = {outv[4], outv[5], outv[6], outv[7]};
    *(f32x4*)(base + p * 96) = wa;
    *(f32x4*)(base + p * 96 + 4) = wb2;
  }
}

// ---------------- Kernel E: dwconv3x3 + gelu-gate + proj_out + residual ----------------
// grid (72, 2) x 256. Residual from X2.
__global__ __launch_bounds__(256) void k_dw_out(
    const float* __restrict__ Hbuf, const float* __restrict__ dww,
    const float* __restrict__ poww, const float* __restrict__ X2,
    float* __restrict__ out) {
  __shared__ float dw[576];
  __shared__ float pw[1024];
  int half = blockIdx.y;
  for (int i = threadIdx.x; i < 576; i += 256) dw[i] = dww[i];
  for (int i = threadIdx.x; i < 1024; i += 256) pw[i] = poww[half * 1024 + i];
  __syncthreads();
  int idx = blockIdx.x * 256 + threadIdx.x;
  int b = idx / NPOS, n = idx % NPOS;
  int y = n / 96, xx = n % 96;
  const float* hb = Hbuf + (size_t)b * CH * NPOS;
  float g[32];
#pragma unroll
  for (int cc = 0; cc < 32; ++cc) {
    float d1 = 0.f, d2 = 0.f;
    for (int dy = -1; dy <= 1; ++dy) {
      int yy = y + dy;
      if (yy < 0 || yy >= 96) continue;
      for (int dx = -1; dx <= 1; ++dx) {
        int xv = xx + dx;
        if (xv < 0 || xv >= 96) continue;
        int ki = (dy + 1) * 3 + (dx + 1);
        d1 += hb[(size_t)cc * NPOS + yy * 96 + xv] * dw[cc * 9 + ki];
        d2 += hb[(size_t)(cc + 32) * NPOS + yy * 96 + xv] * dw[(cc + 32) * 9 + ki];
      }
    }
    g[cc] = gelu_exact(d1) * d2;
  }
  const float* xr = X2 + (size_t)b * CH * NPOS + (size_t)half * 32 * NPOS + n;
  float* ob = out + (size_t)b * CH * NPOS + (size_t)half * 32 * NPOS + n;
  for (int oo = 0; oo < 32; ++oo) {
    float acc = xr[oo * NPOS];
#pragma unroll
    for (int cg = 0; cg < 32; ++cg) acc += pw[oo * 32 + cg] * g[cg];
    ob[oo * NPOS] = acc;
  }
}

extern "C" void kernel_launch(void* const* d_in, const int* in_sizes, int n_in,
                              void* d_out, int out_size, void* d_ws, size_t ws_size,
                              hipStream_t stream) {
  const float* x    = (const float*)d_in[0];
  const float* ln1w = (const float*)d_in[1];
  const float* ln1b = (const float*)d_in[2];
  const float* ln2w = (const float*)d_in[3];
  const float* ln2b = (const float*)d_in[4];
  const float* qw   = (const float*)d_in[5];
  const float* qb   = (const float*)d_in[6];
  const float* kw   = (const float*)d_in[7];
  const float* kb   = (const float*)d_in[8];
  const float* vw   = (const float*)d_in[9];
  const float* vb   = (const float*)d_in[10];
  const float* fftw = (const float*)d_in[11];
  const float* piw  = (const float*)d_in[12];
  const float* dww  = (const float*)d_in[13];
  const float* poww = (const float*)d_in[14];

  short* Qg  = (short*)d_ws;                         // [NTOT][64] bf16 (2.36 MB each)
  short* Kg  = Qg + (size_t)NTOT * 64;
  short* Vg  = Kg + (size_t)NTOT * 64;
  short* PoT = Vg + (size_t)NTOT * 64;               // [NSPLIT][64][NTOT] bf16 (9.44 MB)
  float* Pl  = (float*)(PoT + (size_t)NSPLIT * 64 * NTOT);  // [NSPLIT][NTOT] f32
  float* X2  = Pl + (size_t)NSPLIT * NTOT;           // [b][c][n] f32 (9.44 MB)
  float* Hbuf = X2 + (size_t)NTOT * 64;              // [b][c][n] f32 (9.44 MB)

  k_ln_qkv<<<dim3(72, 3), 256, 0, stream>>>(x, ln1w, ln1b, qw, qb, kw, kb, vw, vb, Qg, Kg, Vg);
  k_attn<<<dim3(72, 2, NSPLIT), 256, 0, stream>>>(Qg, Kg, Vg, PoT, Pl);
  k_res_ln2_proj<<<dim3(72, 2), 256, 0, stream>>>(x, PoT, Pl, ln2w, ln2b, piw, X2, Hbuf);
  k_fft<<<dim3(288), 64, 0, stream>>>(Hbuf, fftw);
  k_dw_out<<<dim3(72, 2), 256, 0, stream>>>(Hbuf, dww, poww, X2, (float*)d_out);
}

// Round 11
// 327.249 us; speedup vs baseline: 4.2940x; 1.0159x over previous
//
#include <hip/hip_runtime.h>
#include <hip/hip_bf16.h>
#include <math.h>

#define CH 64
#define NPOS 9216   // 96*96
#define NTOT 18432  // 2*9216
#define NSPLIT 8
#define TILES_PER_SPLIT 18   // 144/8
#define LOG2E 1.4426950408889634f

typedef short bf16x8 __attribute__((ext_vector_type(8)));
typedef short bf16x4 __attribute__((ext_vector_type(4)));
typedef float f32x4 __attribute__((ext_vector_type(4)));
typedef int   i32x4 __attribute__((ext_vector_type(4)));
typedef unsigned int u32;

__device__ __forceinline__ float bf2f(short s) {
  unsigned int u = ((unsigned int)(unsigned short)s) << 16;
  return __builtin_bit_cast(float, u);
}
__device__ __forceinline__ short f2bf(float f) {
  unsigned int u = __builtin_bit_cast(unsigned int, f);
  unsigned int r = (u + 0x7fffu + ((u >> 16) & 1u)) >> 16;  // RNE
  return (short)r;
}
__device__ __forceinline__ float gelu_exact(float x) {
  return 0.5f * x * (1.f + erff(x * 0.70710678118654752440f));
}

// Verified: inputs fp32, output fp32, plain NCHW. R10: attn grid-capped occupancy
// (2.25 w/SIMD), Kt b128 8-way conflicts (96cyc/iter), exposed staging latency.
// R11: NSPLIT 8 + reg prefetch + Kt stride 40w + uniform s_load weights (no LDS).

// ---------------- Kernel A: LN1 + QKV projection ----------------
// grid (72, 3) x 256. Weights read with uniform indices -> s_load (SMEM).
__global__ __launch_bounds__(256) void k_ln_qkv(
    const float* __restrict__ x, const float* __restrict__ ln1w, const float* __restrict__ ln1b,
    const float* __restrict__ qw, const float* __restrict__ qb,
    const float* __restrict__ kw, const float* __restrict__ kb,
    const float* __restrict__ vw, const float* __restrict__ vb,
    short* __restrict__ Qg, short* __restrict__ Kg, short* __restrict__ Vg) {
  int mat = blockIdx.y;
  const float* wsrc = (mat == 0) ? qw : (mat == 1) ? kw : vw;
  const float* bsrc = (mat == 0) ? qb : (mat == 1) ? kb : vb;
  int idx = blockIdx.x * 256 + threadIdx.x;
  int b = idx / NPOS, n = idx % NPOS;
  const float* xb = x + (size_t)b * CH * NPOS + n;
  float xr[64];
  float mu = 0.f;
#pragma unroll
  for (int c = 0; c < 64; ++c) { float v = xb[c * NPOS]; xr[c] = v; mu += v; }
  mu *= (1.f / 64.f);
  float var = 0.f;
#pragma unroll
  for (int c = 0; c < 64; ++c) { float d = xr[c] - mu; var += d * d; }
  float rstd = rsqrtf(var * (1.f / 64.f) + 1e-5f);
#pragma unroll
  for (int c = 0; c < 64; ++c) xr[c] = (xr[c] - mu) * rstd * ln1w[c] + ln1b[c];
  float kscale = (mat == 1) ? LOG2E : 1.f;
  short* outp = ((mat == 0) ? Qg : (mat == 1) ? Kg : Vg) + (size_t)idx * 64;
  for (int o2 = 0; o2 < 8; ++o2) {
    bf16x8 v8;
#pragma unroll
    for (int j = 0; j < 8; ++j) {
      int o = o2 * 8 + j;
      float acc = bsrc[o];
      const float* wrow = wsrc + o * 64;
#pragma unroll
      for (int c = 0; c < 64; ++c) acc += wrow[c] * xr[c];
      v8[j] = f2bf(acc * kscale);
    }
    *(bf16x8*)(outp + o2 * 8) = v8;
  }
}

// ---------------- Kernel B: MFMA flash attention, S^T scheme + prefetch ----------------
// grid (72, 2, NSPLIT) x 256. 128 q/block, 32 q/wave. S^T=K.Q^T (16x16x32);
// p=exp2(s) packed bf16 feeds PV (16x16x16) as B from regs. O^T accum.
// Kt stride 40 words (<=2-way banks); V^T stride 36 (2-way). Reg prefetch of next tile.
#define LDPK 80   // shorts per Kt row (64 data + 16 pad): bank = (8L+4q)%32
#define LDP  72   // shorts per Vt row
__global__ __launch_bounds__(256) void k_attn(
    const short* __restrict__ Qg, const short* __restrict__ Kg, const short* __restrict__ Vg,
    u32* __restrict__ PoT, float* __restrict__ Pl) {
  __shared__ __align__(16) short Kt[64 * LDPK];  // [key][dim]
  __shared__ __align__(16) short Vt[64 * LDP];   // [dim][key]
  int b = blockIdx.y;
  int n0 = blockIdx.x * 128;
  int ks = blockIdx.z;
  int tid = threadIdx.x;
  int w = tid >> 6, lane = tid & 63;
  int L = lane & 15, quad = lane >> 4;

  bf16x8 qa[2][2];
#pragma unroll
  for (int qt = 0; qt < 2; ++qt) {
    const short* qb_ = Qg + ((size_t)(b * NPOS + n0 + w * 32 + qt * 16 + L)) * 64;
    qa[qt][0] = *(const bf16x8*)(qb_ + quad * 8);
    qa[qt][1] = *(const bf16x8*)(qb_ + 32 + quad * 8);
  }

  f32x4 o[2][4];
#pragma unroll
  for (int qt = 0; qt < 2; ++qt)
#pragma unroll
    for (int nb = 0; nb < 4; ++nb) o[qt][nb] = (f32x4){0.f, 0.f, 0.f, 0.f};
  float rl[2] = {0.f, 0.f};

  int k2 = tid & 31, dg = tid >> 5;
  // prefetch registers
  i32x4 kr0, kr1;
  bf16x8 pv0, pv1;
  {
    int kt = ks * TILES_PER_SPLIT;
    const i32x4* src = (const i32x4*)(Kg + ((size_t)(b * NPOS + kt * 64)) * 64);
    kr0 = src[tid]; kr1 = src[tid + 256];
    const short* vs0 = Vg + ((size_t)(b * NPOS + kt * 64 + 2 * k2)) * 64 + dg * 8;
    pv0 = *(const bf16x8*)vs0; pv1 = *(const bf16x8*)(vs0 + 64);
  }

  for (int t = 0; t < TILES_PER_SPLIT; ++t) {
    __syncthreads();
    {
      i32x4* dst = (i32x4*)Kt;
      dst[(tid >> 3) * 10 + (tid & 7)] = kr0;            // keys 0..31
      dst[((tid + 256) >> 3) * 10 + (tid & 7)] = kr1;    // keys 32..63
      u32* vtw = (u32*)Vt;
      const u32* v0w = (const u32*)&pv0;
      const u32* v1w = (const u32*)&pv1;
#pragma unroll
      for (int j = 0; j < 8; ++j) {
        u32 pk = (j & 1) ? __builtin_amdgcn_perm(v1w[j >> 1], v0w[j >> 1], 0x07060302u)
                         : __builtin_amdgcn_perm(v1w[j >> 1], v0w[j >> 1], 0x05040100u);
        vtw[(dg * 8 + j) * 36 + k2] = pk;
      }
    }
    __syncthreads();
    if (t + 1 < TILES_PER_SPLIT) {   // prefetch next tile (overlaps compute)
      int kt = ks * TILES_PER_SPLIT + t + 1;
      const i32x4* src = (const i32x4*)(Kg + ((size_t)(b * NPOS + kt * 64)) * 64);
      kr0 = src[tid]; kr1 = src[tid + 256];
      const short* vs0 = Vg + ((size_t)(b * NPOS + kt * 64 + 2 * k2)) * 64 + dg * 8;
      pv0 = *(const bf16x8*)vs0; pv1 = *(const bf16x8*)(vs0 + 64);
    }

    const i32x4* kt4 = (const i32x4*)Kt;
#pragma unroll
    for (int kti = 0; kti < 4; ++kti) {
      bf16x8 kf0 = __builtin_bit_cast(bf16x8, kt4[(kti * 16 + L) * 10 + quad]);
      bf16x8 kf1 = __builtin_bit_cast(bf16x8, kt4[(kti * 16 + L) * 10 + 4 + quad]);
      bf16x4 pp[2];
#pragma unroll
      for (int qt = 0; qt < 2; ++qt) {
        f32x4 st = {0.f, 0.f, 0.f, 0.f};
        st = __builtin_amdgcn_mfma_f32_16x16x32_bf16(kf0, qa[qt][0], st, 0, 0, 0);
        st = __builtin_amdgcn_mfma_f32_16x16x32_bf16(kf1, qa[qt][1], st, 0, 0, 0);
        float p0 = exp2f(st[0]), p1 = exp2f(st[1]), p2 = exp2f(st[2]), p3 = exp2f(st[3]);
        rl[qt] += (p0 + p1) + (p2 + p3);
        u32 lo = __builtin_amdgcn_perm(__builtin_bit_cast(u32, p1), __builtin_bit_cast(u32, p0), 0x07060302u);
        u32 hi = __builtin_amdgcn_perm(__builtin_bit_cast(u32, p3), __builtin_bit_cast(u32, p2), 0x07060302u);
        u32 pr[2] = {lo, hi};
        pp[qt] = __builtin_bit_cast(bf16x4, pr);
      }
#pragma unroll
      for (int nb = 0; nb < 4; ++nb) {
        bf16x4 va = *(const bf16x4*)(Vt + (nb * 16 + L) * LDP + kti * 16 + quad * 4);
#pragma unroll
        for (int qt = 0; qt < 2; ++qt)
          o[qt][nb] = __builtin_amdgcn_mfma_f32_16x16x16bf16_1k(va, pp[qt], o[qt][nb], 0, 0, 0);
      }
    }
  }

#pragma unroll
  for (int qt = 0; qt < 2; ++qt) {
    rl[qt] += __shfl_xor(rl[qt], 16);
    rl[qt] += __shfl_xor(rl[qt], 32);
  }

  // store O^T partials packed as bf16 pairs: d32 = nb*8 + quad*2 + ip -> ch = nb*16+quad*4+2ip
#pragma unroll
  for (int qt = 0; qt < 2; ++qt) {
    int qg = b * NPOS + n0 + w * 32 + qt * 16 + L;
#pragma unroll
    for (int nb = 0; nb < 4; ++nb)
#pragma unroll
      for (int ip = 0; ip < 2; ++ip) {
        u32 pk = ((u32)(unsigned short)f2bf(o[qt][nb][2 * ip + 1]) << 16) |
                 (u32)(unsigned short)f2bf(o[qt][nb][2 * ip]);
        int d32 = nb * 8 + quad * 2 + ip;
        PoT[((size_t)(ks * 32 + d32)) * NTOT + qg] = pk;
      }
    if (quad == 0) Pl[(size_t)ks * NTOT + qg] = rl[qt];
  }
}

// ---------------- Kernel C: merge + residual + LN2 + proj_in (+X2) ----------------
// grid (72, 2) x 256. Uniform s_load weights; PoT packed-pair merge.
__global__ __launch_bounds__(256) void k_res_ln2_proj(
    const float* __restrict__ x, const u32* __restrict__ PoT, const float* __restrict__ Pl,
    const float* __restrict__ ln2w, const float* __restrict__ ln2b,
    const float* __restrict__ piw,
    float* __restrict__ X2, float* __restrict__ Hbuf) {
  int part = blockIdx.y;
  int idx = blockIdx.x * 256 + threadIdx.x;
  int b = idx / NPOS, n = idx % NPOS;
  const float* xb = x + (size_t)b * CH * NPOS + n;
  float lsum = 0.f;
#pragma unroll
  for (int s = 0; s < NSPLIT; ++s) lsum += Pl[(size_t)s * NTOT + idx];
  float inv = 1.f / lsum;
  float xr[64];
#pragma unroll
  for (int d32 = 0; d32 < 32; ++d32) {
    float a0 = 0.f, a1 = 0.f;
#pragma unroll
    for (int s = 0; s < NSPLIT; ++s) {
      u32 v = PoT[((size_t)(s * 32 + d32)) * NTOT + idx];
      a0 += __builtin_bit_cast(float, v << 16);
      a1 += __builtin_bit_cast(float, v & 0xffff0000u);
    }
    int c = ((d32 >> 3) * 16) + (((d32 >> 1) & 3) * 4) + ((d32 & 1) * 2);
    xr[c] = xb[c * NPOS] + a0 * inv;
    xr[c + 1] = xb[(c + 1) * NPOS] + a1 * inv;
  }
  float mu = 0.f;
#pragma unroll
  for (int c = 0; c < 64; ++c) mu += xr[c];
  if (part == 0) {
    float* xo = X2 + (size_t)b * CH * NPOS + n;
#pragma unroll
    for (int c = 0; c < 64; ++c) xo[c * NPOS] = xr[c];
  }
  mu *= (1.f / 64.f);
  float var = 0.f;
#pragma unroll
  for (int c = 0; c < 64; ++c) { float d = xr[c] - mu; var += d * d; }
  float rstd = rsqrtf(var * (1.f / 64.f) + 1e-5f);
#pragma unroll
  for (int c = 0; c < 64; ++c) xr[c] = (xr[c] - mu) * rstd * ln2w[c] + ln2b[c];
  float* hb = Hbuf + (size_t)b * CH * NPOS + (size_t)part * 32 * NPOS + n;
  for (int oo = 0; oo < 32; ++oo) {
    float acc = 0.f;
    const float* wrow = piw + part * 2048 + oo * 64;
#pragma unroll
    for (int c = 0; c < 64; ++c) acc += wrow[c] * xr[c];
    hb[oo * NPOS] = acc;
  }
}

// ---------------- Kernel D: per-patch spectral filter ----------------
// grid (288) x 64. wb fastest -> coalesced 384B spans.
__global__ __launch_bounds__(64) void k_fft(float* __restrict__ Hbuf, const float* __restrict__ fftw) {
  int idx = blockIdx.x * 64 + threadIdx.x;
  int wb = idx % 12;
  int t = idx / 12;
  int hb = t % 12;
  int t2 = t / 12;
  int c = t2 % 64;
  int b = t2 / 64;
  float* base = Hbuf + (size_t)(b * CH + c) * NPOS + (hb * 8) * 96 + wb * 8;
  const float r = 0.70710678118654752440f;
  const float CO[8] = {1.f, r, 0.f, -r, -1.f, -r, 0.f, r};
  const float SI[8] = {0.f, r, 1.f, r, 0.f, -r, -1.f, -r};
  float Ar[8][5], Ai[8][5];
#pragma unroll
  for (int p = 0; p < 8; ++p) {
    f32x4 ra = *(const f32x4*)(base + p * 96);
    f32x4 rb = *(const f32x4*)(base + p * 96 + 4);
    float row[8] = {ra[0], ra[1], ra[2], ra[3], rb[0], rb[1], rb[2], rb[3]};
#pragma unroll
    for (int v = 0; v < 5; ++v) {
      float sr = 0.f, si = 0.f;
#pragma unroll
      for (int q = 0; q < 8; ++q) {
        int k = (q * v) & 7;
        sr += row[q] * CO[k];
        si -= row[q] * SI[k];
      }
      Ar[p][v] = sr;
      Ai[p][v] = si;
    }
  }
  const float* wp = fftw + c * 40;
#pragma unroll
  for (int v = 0; v < 5; ++v) {
    float Br[8], Bi[8];
#pragma unroll
    for (int u = 0; u < 8; ++u) {
      float cr = 0.f, ci = 0.f;
#pragma unroll
      for (int p = 0; p < 8; ++p) {
        int k = (p * u) & 7;
        float cc = CO[k], ss = SI[k];
        cr += Ar[p][v] * cc + Ai[p][v] * ss;
        ci += Ai[p][v] * cc - Ar[p][v] * ss;
      }
      float wv = wp[u * 5 + v];
      Br[u] = cr * wv;
      Bi[u] = ci * wv;
    }
#pragma unroll
    for (int p = 0; p < 8; ++p) {
      float yr = 0.f, yi = 0.f;
#pragma unroll
      for (int u = 0; u < 8; ++u) {
        int k = (p * u) & 7;
        float cc = CO[k], ss = SI[k];
        yr += Br[u] * cc - Bi[u] * ss;
        yi += Bi[u] * cc + Br[u] * ss;
      }
      Ar[p][v] = yr * 0.125f;
      Ai[p][v] = yi * 0.125f;
    }
  }
#pragma unroll
  for (int p = 0; p < 8; ++p) {
    float outv[8];
#pragma unroll
    for (int q = 0; q < 8; ++q) {
      float acc = Ar[p][0] + ((q & 1) ? -Ar[p][4] : Ar[p][4]);
#pragma unroll
      for (int v = 1; v < 4; ++v) {
        int k = (q * v) & 7;
        acc += 2.f * (Ar[p][v] * CO[k] - Ai[p][v] * SI[k]);
      }
      outv[q] = acc * 0.125f;
    }
    f32x4 wa = {outv[0], outv[1], outv[2], outv[3]};
    f32x4 wb2 = {outv[4], outv[5], outv[6], outv[7]};
    *(f32x4*)(base + p * 96) = wa;
    *(f32x4*)(base + p * 96 + 4) = wb2;
  }
}

// ---------------- Kernel E: dwconv3x3 + gelu-gate + proj_out + residual ----------------
// grid (72, 2) x 256. Uniform s_load weights (hoisted out of divergent bounds loops).
__global__ __launch_bounds__(256) void k_dw_out(
    const float* __restrict__ Hbuf, const float* __restrict__ dww,
    const float* __restrict__ poww, const float* __restrict__ X2,
    float* __restrict__ out) {
  int half = blockIdx.y;
  int idx = blockIdx.x * 256 + threadIdx.x;
  int b = idx / NPOS, n = idx % NPOS;
  int y = n / 96, xx = n % 96;
  const float* hb = Hbuf + (size_t)b * CH * NPOS;
  float g[32];
#pragma unroll
  for (int cc = 0; cc < 32; ++cc) {
    float wd1[9], wd2[9];
#pragma unroll
    for (int ki = 0; ki < 9; ++ki) {     // uniform flow -> s_load
      wd1[ki] = dww[cc * 9 + ki];
      wd2[ki] = dww[(cc + 32) * 9 + ki];
    }
    float d1 = 0.f, d2 = 0.f;
    for (int dy = -1; dy <= 1; ++dy) {
      int yy = y + dy;
      if (yy < 0 || yy >= 96) continue;
      for (int dx = -1; dx <= 1; ++dx) {
        int xv = xx + dx;
        if (xv < 0 || xv >= 96) continue;
        int ki = (dy + 1) * 3 + (dx + 1);
        d1 += hb[(size_t)cc * NPOS + yy * 96 + xv] * wd1[ki];
        d2 += hb[(size_t)(cc + 32) * NPOS + yy * 96 + xv] * wd2[ki];
      }
    }
    g[cc] = gelu_exact(d1) * d2;
  }
  const float* xr = X2 + (size_t)b * CH * NPOS + (size_t)half * 32 * NPOS + n;
  float* ob = out + (size_t)b * CH * NPOS + (size_t)half * 32 * NPOS + n;
  for (int oo = 0; oo < 32; ++oo) {
    float acc = xr[oo * NPOS];
    const float* prow = poww + half * 1024 + oo * 32;
#pragma unroll
    for (int cg = 0; cg < 32; ++cg) acc += prow[cg] * g[cg];
    ob[oo * NPOS] = acc;
  }
}

extern "C" void kernel_launch(void* const* d_in, const int* in_sizes, int n_in,
                              void* d_out, int out_size, void* d_ws, size_t ws_size,
                              hipStream_t stream) {
  const float* x    = (const float*)d_in[0];
  const float* ln1w = (const float*)d_in[1];
  const float* ln1b = (const float*)d_in[2];
  const float* ln2w = (const float*)d_in[3];
  const float* ln2b = (const float*)d_in[4];
  const float* qw   = (const float*)d_in[5];
  const float* qb   = (const float*)d_in[6];
  const float* kw   = (const float*)d_in[7];
  const float* kb   = (const float*)d_in[8];
  const float* vw   = (const float*)d_in[9];
  const float* vb   = (const float*)d_in[10];
  const float* fftw = (const float*)d_in[11];
  const float* piw  = (const float*)d_in[12];
  const float* dww  = (const float*)d_in[13];
  const float* poww = (const float*)d_in[14];

  short* Qg  = (short*)d_ws;                         // [NTOT][64] bf16
  short* Kg  = Qg + (size_t)NTOT * 64;
  short* Vg  = Kg + (size_t)NTOT * 64;
  u32*   PoT = (u32*)(Vg + (size_t)NTOT * 64);       // [NSPLIT][32][NTOT] u32 pairs (18.9 MB)
  float* Pl  = (float*)(PoT + (size_t)NSPLIT * 32 * NTOT);  // [NSPLIT][NTOT] f32
  float* X2  = Pl + (size_t)NSPLIT * NTOT;           // [b][c][n] f32 (4.72 MB)
  float* Hbuf = X2 + (size_t)NTOT * 64;              // [b][c][n] f32 (4.72 MB)

  k_ln_qkv<<<dim3(72, 3), 256, 0, stream>>>(x, ln1w, ln1b, qw, qb, kw, kb, vw, vb, Qg, Kg, Vg);
  k_attn<<<dim3(72, 2, NSPLIT), 256, 0, stream>>>(Qg, Kg, Vg, PoT, Pl);
  k_res_ln2_proj<<<dim3(72, 2), 256, 0, stream>>>(x, PoT, Pl, ln2w, ln2b, piw, X2, Hbuf);
  k_fft<<<dim3(288), 64, 0, stream>>>(Hbuf, fftw);
  k_dw_out<<<dim3(72, 2), 256, 0, stream>>>(Hbuf, dww, poww, X2, (float*)d_out);
}

// Round 12
// 223.666 us; speedup vs baseline: 6.2826x; 1.4631x over previous
//
#include <hip/hip_runtime.h>
#include <hip/hip_bf16.h>
#include <math.h>

#define CH 64
#define NPOS 9216   // 96*96
#define NTOT 18432  // 2*9216
#define NSPLIT 8
#define TILES_PER_SPLIT 18   // 144/8
#define LOG2E 1.4426950408889634f

typedef short bf16x8 __attribute__((ext_vector_type(8)));
typedef short bf16x4 __attribute__((ext_vector_type(4)));
typedef float f32x4 __attribute__((ext_vector_type(4)));
typedef int   i32x4 __attribute__((ext_vector_type(4)));
typedef unsigned int u32;

__device__ __forceinline__ float bf2f(short s) {
  unsigned int u = ((unsigned int)(unsigned short)s) << 16;
  return __builtin_bit_cast(float, u);
}
__device__ __forceinline__ short f2bf(float f) {
  unsigned int u = __builtin_bit_cast(unsigned int, f);
  unsigned int r = (u + 0x7fffu + ((u >> 16) & 1u)) >> 16;  // RNE
  return (short)r;
}
__device__ __forceinline__ float gelu_exact(float x) {
  return 0.5f * x * (1.f + erff(x * 0.70710678118654752440f));
}

// R11: attn VALU-bound (libm exp2f fixup code); other 4 kernels ~231us, all
// latency-starved tiny grids. R12: builtin v_exp_f32; A split x2; C rewritten
// (coalesced single-pass merge + LDS LN); E split into channel-parallel E1 + E2.

// ---------------- Kernel A: LN1 + QKV projection ----------------
// grid (72, 3, 2) x 256. Uniform s_load weights. half = out-channel half.
__global__ __launch_bounds__(256) void k_ln_qkv(
    const float* __restrict__ x, const float* __restrict__ ln1w, const float* __restrict__ ln1b,
    const float* __restrict__ qw, const float* __restrict__ qb,
    const float* __restrict__ kw, const float* __restrict__ kb,
    const float* __restrict__ vw, const float* __restrict__ vb,
    short* __restrict__ Qg, short* __restrict__ Kg, short* __restrict__ Vg) {
  int mat = blockIdx.y;
  int half = blockIdx.z;
  const float* wsrc = (mat == 0) ? qw : (mat == 1) ? kw : vw;
  const float* bsrc = (mat == 0) ? qb : (mat == 1) ? kb : vb;
  int idx = blockIdx.x * 256 + threadIdx.x;
  int b = idx / NPOS, n = idx % NPOS;
  const float* xb = x + (size_t)b * CH * NPOS + n;
  float xr[64];
  float mu = 0.f;
#pragma unroll
  for (int c = 0; c < 64; ++c) { float v = xb[c * NPOS]; xr[c] = v; mu += v; }
  mu *= (1.f / 64.f);
  float var = 0.f;
#pragma unroll
  for (int c = 0; c < 64; ++c) { float d = xr[c] - mu; var += d * d; }
  float rstd = rsqrtf(var * (1.f / 64.f) + 1e-5f);
#pragma unroll
  for (int c = 0; c < 64; ++c) xr[c] = (xr[c] - mu) * rstd * ln1w[c] + ln1b[c];
  float kscale = (mat == 1) ? LOG2E : 1.f;
  short* outp = ((mat == 0) ? Qg : (mat == 1) ? Kg : Vg) + (size_t)idx * 64 + half * 32;
  for (int o2 = 0; o2 < 4; ++o2) {
    bf16x8 v8;
#pragma unroll
    for (int j = 0; j < 8; ++j) {
      int o = half * 32 + o2 * 8 + j;
      float acc = bsrc[o];
      const float* wrow = wsrc + o * 64;
#pragma unroll
      for (int c = 0; c < 64; ++c) acc += wrow[c] * xr[c];
      v8[j] = f2bf(acc * kscale);
    }
    *(bf16x8*)(outp + o2 * 8) = v8;
  }
}

// ---------------- Kernel B: MFMA flash attention ----------------
// grid (72, 2, NSPLIT) x 256. 128 q/block, 32 q/wave. Raw v_exp_f32 softmax.
#define LDPK 80
#define LDP  72
__global__ __launch_bounds__(256) void k_attn(
    const short* __restrict__ Qg, const short* __restrict__ Kg, const short* __restrict__ Vg,
    u32* __restrict__ PoT, float* __restrict__ Pl) {
  __shared__ __align__(16) short Kt[64 * LDPK];
  __shared__ __align__(16) short Vt[64 * LDP];
  int b = blockIdx.y;
  int n0 = blockIdx.x * 128;
  int ks = blockIdx.z;
  int tid = threadIdx.x;
  int w = tid >> 6, lane = tid & 63;
  int L = lane & 15, quad = lane >> 4;

  bf16x8 qa[2][2];
#pragma unroll
  for (int qt = 0; qt < 2; ++qt) {
    const short* qb_ = Qg + ((size_t)(b * NPOS + n0 + w * 32 + qt * 16 + L)) * 64;
    qa[qt][0] = *(const bf16x8*)(qb_ + quad * 8);
    qa[qt][1] = *(const bf16x8*)(qb_ + 32 + quad * 8);
  }

  f32x4 o[2][4];
#pragma unroll
  for (int qt = 0; qt < 2; ++qt)
#pragma unroll
    for (int nb = 0; nb < 4; ++nb) o[qt][nb] = (f32x4){0.f, 0.f, 0.f, 0.f};
  float rl[2] = {0.f, 0.f};

  int k2 = tid & 31, dg = tid >> 5;
  i32x4 kr0, kr1;
  bf16x8 pv0, pv1;
  {
    int kt = ks * TILES_PER_SPLIT;
    const i32x4* src = (const i32x4*)(Kg + ((size_t)(b * NPOS + kt * 64)) * 64);
    kr0 = src[tid]; kr1 = src[tid + 256];
    const short* vs0 = Vg + ((size_t)(b * NPOS + kt * 64 + 2 * k2)) * 64 + dg * 8;
    pv0 = *(const bf16x8*)vs0; pv1 = *(const bf16x8*)(vs0 + 64);
  }

  for (int t = 0; t < TILES_PER_SPLIT; ++t) {
    __syncthreads();
    {
      i32x4* dst = (i32x4*)Kt;
      dst[(tid >> 3) * 10 + (tid & 7)] = kr0;
      dst[((tid + 256) >> 3) * 10 + (tid & 7)] = kr1;
      u32* vtw = (u32*)Vt;
      const u32* v0w = (const u32*)&pv0;
      const u32* v1w = (const u32*)&pv1;
#pragma unroll
      for (int j = 0; j < 8; ++j) {
        u32 pk = (j & 1) ? __builtin_amdgcn_perm(v1w[j >> 1], v0w[j >> 1], 0x07060302u)
                         : __builtin_amdgcn_perm(v1w[j >> 1], v0w[j >> 1], 0x05040100u);
        vtw[(dg * 8 + j) * 36 + k2] = pk;
      }
    }
    __syncthreads();
    if (t + 1 < TILES_PER_SPLIT) {
      int kt = ks * TILES_PER_SPLIT + t + 1;
      const i32x4* src = (const i32x4*)(Kg + ((size_t)(b * NPOS + kt * 64)) * 64);
      kr0 = src[tid]; kr1 = src[tid + 256];
      const short* vs0 = Vg + ((size_t)(b * NPOS + kt * 64 + 2 * k2)) * 64 + dg * 8;
      pv0 = *(const bf16x8*)vs0; pv1 = *(const bf16x8*)(vs0 + 64);
    }

    const i32x4* kt4 = (const i32x4*)Kt;
#pragma unroll
    for (int kti = 0; kti < 4; ++kti) {
      bf16x8 kf0 = __builtin_bit_cast(bf16x8, kt4[(kti * 16 + L) * 10 + quad]);
      bf16x8 kf1 = __builtin_bit_cast(bf16x8, kt4[(kti * 16 + L) * 10 + 4 + quad]);
      bf16x4 pp[2];
#pragma unroll
      for (int qt = 0; qt < 2; ++qt) {
        f32x4 st = {0.f, 0.f, 0.f, 0.f};
        st = __builtin_amdgcn_mfma_f32_16x16x32_bf16(kf0, qa[qt][0], st, 0, 0, 0);
        st = __builtin_amdgcn_mfma_f32_16x16x32_bf16(kf1, qa[qt][1], st, 0, 0, 0);
        float p0 = __builtin_amdgcn_exp2f(st[0]);
        float p1 = __builtin_amdgcn_exp2f(st[1]);
        float p2 = __builtin_amdgcn_exp2f(st[2]);
        float p3 = __builtin_amdgcn_exp2f(st[3]);
        rl[qt] += (p0 + p1) + (p2 + p3);
        u32 lo = __builtin_amdgcn_perm(__builtin_bit_cast(u32, p1), __builtin_bit_cast(u32, p0), 0x07060302u);
        u32 hi = __builtin_amdgcn_perm(__builtin_bit_cast(u32, p3), __builtin_bit_cast(u32, p2), 0x07060302u);
        u32 pr[2] = {lo, hi};
        pp[qt] = __builtin_bit_cast(bf16x4, pr);
      }
#pragma unroll
      for (int nb = 0; nb < 4; ++nb) {
        bf16x4 va = *(const bf16x4*)(Vt + (nb * 16 + L) * LDP + kti * 16 + quad * 4);
#pragma unroll
        for (int qt = 0; qt < 2; ++qt)
          o[qt][nb] = __builtin_amdgcn_mfma_f32_16x16x16bf16_1k(va, pp[qt], o[qt][nb], 0, 0, 0);
      }
    }
  }

#pragma unroll
  for (int qt = 0; qt < 2; ++qt) {
    rl[qt] += __shfl_xor(rl[qt], 16);
    rl[qt] += __shfl_xor(rl[qt], 32);
  }

#pragma unroll
  for (int qt = 0; qt < 2; ++qt) {
    int qg = b * NPOS + n0 + w * 32 + qt * 16 + L;
#pragma unroll
    for (int nb = 0; nb < 4; ++nb)
#pragma unroll
      for (int ip = 0; ip < 2; ++ip) {
        u32 pk = ((u32)(unsigned short)f2bf(o[qt][nb][2 * ip + 1]) << 16) |
                 (u32)(unsigned short)f2bf(o[qt][nb][2 * ip]);
        int d32 = nb * 8 + quad * 2 + ip;
        PoT[((size_t)(ks * 32 + d32)) * NTOT + qg] = pk;
      }
    if (quad == 0) Pl[(size_t)ks * NTOT + qg] = rl[qt];
  }
}

// ---------------- Kernel C: merge + residual + LN2 + proj_in (+X2) ----------------
// grid (288) x 256. Block = 64 positions; wave w owns channels 16w..16w+15.
// Single-pass coalesced PoT merge; cross-wave LN via LDS; phase-2 GEMM from LDS.
__global__ __launch_bounds__(256) void k_res_ln2_proj(
    const float* __restrict__ x, const u32* __restrict__ PoT, const float* __restrict__ Pl,
    const float* __restrict__ ln2w, const float* __restrict__ ln2b,
    const float* __restrict__ piw,
    float* __restrict__ X2, float* __restrict__ Hbuf) {
  __shared__ float s1a[4 * 64], s2a[4 * 64];
  __shared__ float xn[64 * 65];
  int t = threadIdx.x;
  int w = t >> 6;       // wave = channel group (16 channels)
  int p = t & 63;       // position within block
  int n0 = blockIdx.x * 64;
  int q = n0 + p;
  int b = q / NPOS, n = q % NPOS;

  float lsum = 0.f;
#pragma unroll
  for (int s = 0; s < NSPLIT; ++s) lsum += Pl[(size_t)s * NTOT + q];
  float inv = 1.f / lsum;

  const float* xb = x + (size_t)b * CH * NPOS + n;
  float xr[16];
  float s1 = 0.f, s2 = 0.f;
#pragma unroll
  for (int j2 = 0; j2 < 8; ++j2) {
    float a0 = 0.f, a1 = 0.f;
#pragma unroll
    for (int s = 0; s < NSPLIT; ++s) {
      u32 v = PoT[((size_t)(s * 32 + w * 8 + j2)) * NTOT + q];
      a0 += __builtin_bit_cast(float, v << 16);
      a1 += __builtin_bit_cast(float, v & 0xffff0000u);
    }
    int cl = 2 * j2;                   // local channel (within wave's 16)
    int c = w * 16 + cl;               // global channel
    float v0 = xb[(size_t)c * NPOS] + a0 * inv;
    float v1 = xb[(size_t)(c + 1) * NPOS] + a1 * inv;
    xr[cl] = v0; xr[cl + 1] = v1;
    s1 += v0 + v1;
    s2 += v0 * v0 + v1 * v1;
  }
  s1a[w * 64 + p] = s1;
  s2a[w * 64 + p] = s2;
  // write X2 (residual) — coalesced per channel
  {
    float* xo = X2 + (size_t)b * CH * NPOS + n;
#pragma unroll
    for (int cl = 0; cl < 16; ++cl) xo[(size_t)(w * 16 + cl) * NPOS] = xr[cl];
  }
  __syncthreads();
  float mu = 0.f, m2 = 0.f;
#pragma unroll
  for (int ww = 0; ww < 4; ++ww) { mu += s1a[ww * 64 + p]; m2 += s2a[ww * 64 + p]; }
  mu *= (1.f / 64.f);
  float var = m2 * (1.f / 64.f) - mu * mu;
  float rstd = rsqrtf(var + 1e-5f);
#pragma unroll
  for (int cl = 0; cl < 16; ++cl) {
    int c = w * 16 + cl;
    xn[p * 65 + c] = (xr[cl] - mu) * rstd * ln2w[c] + ln2b[c];
  }
  __syncthreads();
  // phase 2: GEMM — thread computes 16 out-channels (group w) for position p
  float xv[64];
#pragma unroll
  for (int c = 0; c < 64; ++c) xv[c] = xn[p * 65 + c];
  float* hb = Hbuf + (size_t)b * CH * NPOS + n;
  for (int oo = 0; oo < 16; ++oo) {
    int oc = w * 16 + oo;
    const float* wrow = piw + oc * 64;
    float acc = 0.f;
#pragma unroll
    for (int c = 0; c < 64; ++c) acc += wrow[c] * xv[c];
    hb[(size_t)oc * NPOS] = acc;
  }
}

// ---------------- Kernel D: per-patch spectral filter ----------------
// grid (288) x 64.
__global__ __launch_bounds__(64) void k_fft(float* __restrict__ Hbuf, const float* __restrict__ fftw) {
  int idx = blockIdx.x * 64 + threadIdx.x;
  int wb = idx % 12;
  int t = idx / 12;
  int hb = t % 12;
  int t2 = t / 12;
  int c = t2 % 64;
  int b = t2 / 64;
  float* base = Hbuf + (size_t)(b * CH + c) * NPOS + (hb * 8) * 96 + wb * 8;
  const float r = 0.70710678118654752440f;
  const float CO[8] = {1.f, r, 0.f, -r, -1.f, -r, 0.f, r};
  const float SI[8] = {0.f, r, 1.f, r, 0.f, -r, -1.f, -r};
  float Ar[8][5], Ai[8][5];
#pragma unroll
  for (int p = 0; p < 8; ++p) {
    f32x4 ra = *(const f32x4*)(base + p * 96);
    f32x4 rb = *(const f32x4*)(base + p * 96 + 4);
    float row[8] = {ra[0], ra[1], ra[2], ra[3], rb[0], rb[1], rb[2], rb[3]};
#pragma unroll
    for (int v = 0; v < 5; ++v) {
      float sr = 0.f, si = 0.f;
#pragma unroll
      for (int q = 0; q < 8; ++q) {
        int k = (q * v) & 7;
        sr += row[q] * CO[k];
        si -= row[q] * SI[k];
      }
      Ar[p][v] = sr;
      Ai[p][v] = si;
    }
  }
  const float* wp = fftw + c * 40;
#pragma unroll
  for (int v = 0; v < 5; ++v) {
    float Br[8], Bi[8];
#pragma unroll
    for (int u = 0; u < 8; ++u) {
      float cr = 0.f, ci = 0.f;
#pragma unroll
      for (int p = 0; p < 8; ++p) {
        int k = (p * u) & 7;
        float cc = CO[k], ss = SI[k];
        cr += Ar[p][v] * cc + Ai[p][v] * ss;
        ci += Ai[p][v] * cc - Ar[p][v] * ss;
      }
      float wv = wp[u * 5 + v];
      Br[u] = cr * wv;
      Bi[u] = ci * wv;
    }
#pragma unroll
    for (int p = 0; p < 8; ++p) {
      float yr = 0.f, yi = 0.f;
#pragma unroll
      for (int u = 0; u < 8; ++u) {
        int k = (p * u) & 7;
        float cc = CO[k], ss = SI[k];
        yr += Br[u] * cc - Bi[u] * ss;
        yi += Bi[u] * cc + Br[u] * ss;
      }
      Ar[p][v] = yr * 0.125f;
      Ai[p][v] = yi * 0.125f;
    }
  }
#pragma unroll
  for (int p = 0; p < 8; ++p) {
    float outv[8];
#pragma unroll
    for (int q = 0; q < 8; ++q) {
      float acc = Ar[p][0] + ((q & 1) ? -Ar[p][4] : Ar[p][4]);
#pragma unroll
      for (int v = 1; v < 4; ++v) {
        int k = (q * v) & 7;
        acc += 2.f * (Ar[p][v] * CO[k] - Ai[p][v] * SI[k]);
      }
      outv[q] = acc * 0.125f;
    }
    f32x4 wa = {outv[0], outv[1], outv[2], outv[3]};
    f32x4 wb2 = {outv[4], outv[5], outv[6], outv[7]};
    *(f32x4*)(base + p * 96) = wa;
    *(f32x4*)(base + p * 96 + 4) = wb2;
  }
}

// ---------------- Kernel E1: dwconv3x3 + gelu-gate -> G ----------------
// grid (72, 32) x 256. Channel-parallel: block.y = gate channel cc.
__global__ __launch_bounds__(256) void k_dw_gate(
    const float* __restrict__ Hbuf, const float* __restrict__ dww,
    float* __restrict__ G) {
  int cc = blockIdx.y;
  int q = blockIdx.x * 256 + threadIdx.x;
  int b = q / NPOS, n = q % NPOS;
  int y = n / 96, xx = n % 96;
  const float* h1 = Hbuf + (size_t)(b * CH + cc) * NPOS;
  const float* h2 = Hbuf + (size_t)(b * CH + cc + 32) * NPOS;
  float wd1[9], wd2[9];
#pragma unroll
  for (int ki = 0; ki < 9; ++ki) { wd1[ki] = dww[cc * 9 + ki]; wd2[ki] = dww[(cc + 32) * 9 + ki]; }
  float d1 = 0.f, d2 = 0.f;
  for (int dy = -1; dy <= 1; ++dy) {
    int yy = y + dy;
    if (yy < 0 || yy >= 96) continue;
    for (int dx = -1; dx <= 1; ++dx) {
      int xv = xx + dx;
      if (xv < 0 || xv >= 96) continue;
      int ki = (dy + 1) * 3 + (dx + 1);
      d1 += h1[yy * 96 + xv] * wd1[ki];
      d2 += h2[yy * 96 + xv] * wd2[ki];
    }
  }
  G[(size_t)cc * NTOT + q] = gelu_exact(d1) * d2;
}

// ---------------- Kernel E2: proj_out + residual ----------------
// grid (72, 8) x 256. block.y = out-channel group of 8.
__global__ __launch_bounds__(256) void k_proj_out(
    const float* __restrict__ G, const float* __restrict__ poww,
    const float* __restrict__ X2, float* __restrict__ out) {
  int og = blockIdx.y;
  int q = blockIdx.x * 256 + threadIdx.x;
  int b = q / NPOS, n = q % NPOS;
  float g[32];
#pragma unroll
  for (int cg = 0; cg < 32; ++cg) g[cg] = G[(size_t)cg * NTOT + q];
  const float* xr = X2 + (size_t)b * CH * NPOS + n;
  float* ob = out + (size_t)b * CH * NPOS + n;
#pragma unroll
  for (int j = 0; j < 8; ++j) {
    int oc = og * 8 + j;
    const float* prow = poww + oc * 32;
    float acc = xr[(size_t)oc * NPOS];
#pragma unroll
    for (int cg = 0; cg < 32; ++cg) acc += prow[cg] * g[cg];
    ob[(size_t)oc * NPOS] = acc;
  }
}

extern "C" void kernel_launch(void* const* d_in, const int* in_sizes, int n_in,
                              void* d_out, int out_size, void* d_ws, size_t ws_size,
                              hipStream_t stream) {
  const float* x    = (const float*)d_in[0];
  const float* ln1w = (const float*)d_in[1];
  const float* ln1b = (const float*)d_in[2];
  const float* ln2w = (const float*)d_in[3];
  const float* ln2b = (const float*)d_in[4];
  const float* qw   = (const float*)d_in[5];
  const float* qb   = (const float*)d_in[6];
  const float* kw   = (const float*)d_in[7];
  const float* kb   = (const float*)d_in[8];
  const float* vw   = (const float*)d_in[9];
  const float* vb   = (const float*)d_in[10];
  const float* fftw = (const float*)d_in[11];
  const float* piw  = (const float*)d_in[12];
  const float* dww  = (const float*)d_in[13];
  const float* poww = (const float*)d_in[14];

  short* Qg  = (short*)d_ws;                         // 3 x 2.36 MB bf16
  short* Kg  = Qg + (size_t)NTOT * 64;
  short* Vg  = Kg + (size_t)NTOT * 64;
  u32*   PoT = (u32*)(Vg + (size_t)NTOT * 64);       // [NSPLIT][32][NTOT] u32 (18.9 MB)
  float* Pl  = (float*)(PoT + (size_t)NSPLIT * 32 * NTOT);  // [NSPLIT][NTOT]
  float* X2  = Pl + (size_t)NSPLIT * NTOT;           // 4.72 MB
  float* Hbuf = X2 + (size_t)NTOT * 64;              // 4.72 MB
  float* G   = Hbuf + (size_t)NTOT * 64;             // [32][NTOT] 2.36 MB

  k_ln_qkv<<<dim3(72, 3, 2), 256, 0, stream>>>(x, ln1w, ln1b, qw, qb, kw, kb, vw, vb, Qg, Kg, Vg);
  k_attn<<<dim3(72, 2, NSPLIT), 256, 0, stream>>>(Qg, Kg, Vg, PoT, Pl);
  k_res_ln2_proj<<<dim3(288), 256, 0, stream>>>(x, PoT, Pl, ln2w, ln2b, piw, X2, Hbuf);
  k_fft<<<dim3(288), 64, 0, stream>>>(Hbuf, fftw);
  k_dw_gate<<<dim3(72, 32), 256, 0, stream>>>(Hbuf, dww, G);
  k_proj_out<<<dim3(72, 8), 256, 0, stream>>>(G, poww, X2, (float*)d_out);
}

// Round 13
// 208.966 us; speedup vs baseline: 6.7246x; 1.0703x over previous
//
#include <hip/hip_runtime.h>
#include <hip/hip_bf16.h>
#include <math.h>

#define CH 64
#define NPOS 9216   // 96*96
#define NTOT 18432  // 2*9216
#define NSPLIT 8
#define TILES_PER_SPLIT 18   // 144/8
#define LOG2E 1.4426950408889634f

typedef short bf16x8 __attribute__((ext_vector_type(8)));
typedef short bf16x4 __attribute__((ext_vector_type(4)));
typedef float f32x4 __attribute__((ext_vector_type(4)));
typedef int   i32x4 __attribute__((ext_vector_type(4)));
typedef unsigned int u32;

__device__ __forceinline__ float bf2f(short s) {
  unsigned int u = ((unsigned int)(unsigned short)s) << 16;
  return __builtin_bit_cast(float, u);
}
__device__ __forceinline__ short f2bf(float f) {
  unsigned int u = __builtin_bit_cast(unsigned int, f);
  unsigned int r = (u + 0x7fffu + ((u >> 16) & 1u)) >> 16;  // RNE
  return (short)r;
}
__device__ __forceinline__ float gelu_exact(float x) {
  return 0.5f * x * (1.f + erff(x * 0.70710678118654752440f));
}

// R12: attn VALU dominated by V-transpose staging (perm+scatter); C is scalar
// 1024-FMA GEMM at 1.1 w/SIMD. R13: V stored pre-transposed by A -> attn V
// staging pure b128; C phase-2 via MFMA (verified A=rows/B=rows pattern).

// ---------------- Kernel A: LN1 + QKV projection ----------------
// grid (72, 3, 2) x 256. Q/K -> [n][c]; V -> TRANSPOSED [c][n].
__global__ __launch_bounds__(256) void k_ln_qkv(
    const float* __restrict__ x, const float* __restrict__ ln1w, const float* __restrict__ ln1b,
    const float* __restrict__ qw, const float* __restrict__ qb,
    const float* __restrict__ kw, const float* __restrict__ kb,
    const float* __restrict__ vw, const float* __restrict__ vb,
    short* __restrict__ Qg, short* __restrict__ Kg, short* __restrict__ Vgt) {
  int mat = blockIdx.y;
  int half = blockIdx.z;
  const float* wsrc = (mat == 0) ? qw : (mat == 1) ? kw : vw;
  const float* bsrc = (mat == 0) ? qb : (mat == 1) ? kb : vb;
  int idx = blockIdx.x * 256 + threadIdx.x;
  int b = idx / NPOS, n = idx % NPOS;
  const float* xb = x + (size_t)b * CH * NPOS + n;
  float xr[64];
  float mu = 0.f;
#pragma unroll
  for (int c = 0; c < 64; ++c) { float v = xb[c * NPOS]; xr[c] = v; mu += v; }
  mu *= (1.f / 64.f);
  float var = 0.f;
#pragma unroll
  for (int c = 0; c < 64; ++c) { float d = xr[c] - mu; var += d * d; }
  float rstd = rsqrtf(var * (1.f / 64.f) + 1e-5f);
#pragma unroll
  for (int c = 0; c < 64; ++c) xr[c] = (xr[c] - mu) * rstd * ln1w[c] + ln1b[c];
  if (mat == 2) {
    // V: transposed store [c][NTOT]
    for (int o2 = 0; o2 < 4; ++o2) {
#pragma unroll
      for (int j = 0; j < 8; ++j) {
        int o = half * 32 + o2 * 8 + j;
        float acc = bsrc[o];
        const float* wrow = wsrc + o * 64;
#pragma unroll
        for (int c = 0; c < 64; ++c) acc += wrow[c] * xr[c];
        Vgt[(size_t)o * NTOT + idx] = f2bf(acc);
      }
    }
  } else {
    float kscale = (mat == 1) ? LOG2E : 1.f;
    short* outp = ((mat == 0) ? Qg : Kg) + (size_t)idx * 64 + half * 32;
    for (int o2 = 0; o2 < 4; ++o2) {
      bf16x8 v8;
#pragma unroll
      for (int j = 0; j < 8; ++j) {
        int o = half * 32 + o2 * 8 + j;
        float acc = bsrc[o];
        const float* wrow = wsrc + o * 64;
#pragma unroll
        for (int c = 0; c < 64; ++c) acc += wrow[c] * xr[c];
        v8[j] = f2bf(acc * kscale);
      }
      *(bf16x8*)(outp + o2 * 8) = v8;
    }
  }
}

// ---------------- Kernel B: MFMA flash attention ----------------
// grid (72, 2, NSPLIT) x 256. 128 q/block, 32 q/wave. V^T staged via pure b128.
#define LDPK 80
#define LDP  72
__global__ __launch_bounds__(256) void k_attn(
    const short* __restrict__ Qg, const short* __restrict__ Kg, const short* __restrict__ Vgt,
    u32* __restrict__ PoT, float* __restrict__ Pl) {
  __shared__ __align__(16) short Kt[64 * LDPK];
  __shared__ __align__(16) short Vt[64 * LDP];
  int b = blockIdx.y;
  int n0 = blockIdx.x * 128;
  int ks = blockIdx.z;
  int tid = threadIdx.x;
  int w = tid >> 6, lane = tid & 63;
  int L = lane & 15, quad = lane >> 4;

  bf16x8 qa[2][2];
#pragma unroll
  for (int qt = 0; qt < 2; ++qt) {
    const short* qb_ = Qg + ((size_t)(b * NPOS + n0 + w * 32 + qt * 16 + L)) * 64;
    qa[qt][0] = *(const bf16x8*)(qb_ + quad * 8);
    qa[qt][1] = *(const bf16x8*)(qb_ + 32 + quad * 8);
  }

  f32x4 o[2][4];
#pragma unroll
  for (int qt = 0; qt < 2; ++qt)
#pragma unroll
    for (int nb = 0; nb < 4; ++nb) o[qt][nb] = (f32x4){0.f, 0.f, 0.f, 0.f};
  float rl[2] = {0.f, 0.f};

  int c8 = tid & 7, dr = tid >> 3;  // V: dim row dr (+32), 8-key chunk c8
  i32x4 kr0, kr1, vr0, vr1;
  {
    int kt = ks * TILES_PER_SPLIT;
    const i32x4* src = (const i32x4*)(Kg + ((size_t)(b * NPOS + kt * 64)) * 64);
    kr0 = src[tid]; kr1 = src[tid + 256];
    const short* vbase = Vgt + (size_t)b * NPOS + kt * 64 + c8 * 8;
    vr0 = *(const i32x4*)(vbase + (size_t)dr * NTOT);
    vr1 = *(const i32x4*)(vbase + (size_t)(dr + 32) * NTOT);
  }

  for (int t = 0; t < TILES_PER_SPLIT; ++t) {
    __syncthreads();
    {
      i32x4* dst = (i32x4*)Kt;
      dst[(tid >> 3) * 10 + (tid & 7)] = kr0;
      dst[((tid + 256) >> 3) * 10 + (tid & 7)] = kr1;
      i32x4* vdst = (i32x4*)Vt;
      vdst[dr * 9 + c8] = vr0;
      vdst[(dr + 32) * 9 + c8] = vr1;
    }
    __syncthreads();
    if (t + 1 < TILES_PER_SPLIT) {
      int kt = ks * TILES_PER_SPLIT + t + 1;
      const i32x4* src = (const i32x4*)(Kg + ((size_t)(b * NPOS + kt * 64)) * 64);
      kr0 = src[tid]; kr1 = src[tid + 256];
      const short* vbase = Vgt + (size_t)b * NPOS + kt * 64 + c8 * 8;
      vr0 = *(const i32x4*)(vbase + (size_t)dr * NTOT);
      vr1 = *(const i32x4*)(vbase + (size_t)(dr + 32) * NTOT);
    }

    const i32x4* kt4 = (const i32x4*)Kt;
#pragma unroll
    for (int kti = 0; kti < 4; ++kti) {
      bf16x8 kf0 = __builtin_bit_cast(bf16x8, kt4[(kti * 16 + L) * 10 + quad]);
      bf16x8 kf1 = __builtin_bit_cast(bf16x8, kt4[(kti * 16 + L) * 10 + 4 + quad]);
      bf16x4 pp[2];
#pragma unroll
      for (int qt = 0; qt < 2; ++qt) {
        f32x4 st = {0.f, 0.f, 0.f, 0.f};
        st = __builtin_amdgcn_mfma_f32_16x16x32_bf16(kf0, qa[qt][0], st, 0, 0, 0);
        st = __builtin_amdgcn_mfma_f32_16x16x32_bf16(kf1, qa[qt][1], st, 0, 0, 0);
        float p0 = __builtin_amdgcn_exp2f(st[0]);
        float p1 = __builtin_amdgcn_exp2f(st[1]);
        float p2 = __builtin_amdgcn_exp2f(st[2]);
        float p3 = __builtin_amdgcn_exp2f(st[3]);
        rl[qt] += (p0 + p1) + (p2 + p3);
        u32 lo = __builtin_amdgcn_perm(__builtin_bit_cast(u32, p1), __builtin_bit_cast(u32, p0), 0x07060302u);
        u32 hi = __builtin_amdgcn_perm(__builtin_bit_cast(u32, p3), __builtin_bit_cast(u32, p2), 0x07060302u);
        u32 pr[2] = {lo, hi};
        pp[qt] = __builtin_bit_cast(bf16x4, pr);
      }
#pragma unroll
      for (int nb = 0; nb < 4; ++nb) {
        bf16x4 va = *(const bf16x4*)(Vt + (nb * 16 + L) * LDP + kti * 16 + quad * 4);
#pragma unroll
        for (int qt = 0; qt < 2; ++qt)
          o[qt][nb] = __builtin_amdgcn_mfma_f32_16x16x16bf16_1k(va, pp[qt], o[qt][nb], 0, 0, 0);
      }
    }
  }

#pragma unroll
  for (int qt = 0; qt < 2; ++qt) {
    rl[qt] += __shfl_xor(rl[qt], 16);
    rl[qt] += __shfl_xor(rl[qt], 32);
  }

#pragma unroll
  for (int qt = 0; qt < 2; ++qt) {
    int qg = b * NPOS + n0 + w * 32 + qt * 16 + L;
#pragma unroll
    for (int nb = 0; nb < 4; ++nb)
#pragma unroll
      for (int ip = 0; ip < 2; ++ip) {
        u32 pk = ((u32)(unsigned short)f2bf(o[qt][nb][2 * ip + 1]) << 16) |
                 (u32)(unsigned short)f2bf(o[qt][nb][2 * ip]);
        int d32 = nb * 8 + quad * 2 + ip;
        PoT[((size_t)(ks * 32 + d32)) * NTOT + qg] = pk;
      }
    if (quad == 0) Pl[(size_t)ks * NTOT + qg] = rl[qt];
  }
}

// ---------------- Kernel C: merge + residual + LN2 + MFMA proj_in (+X2) ----------------
// grid (288) x 256. Phase1: wave w merges ch 16w..16w+15 for 64 positions, LN via LDS.
// Phase2: MFMA GEMM, A = piw rows (bf16), B = xn rows (bf16 LDS [pos][72]).
__global__ __launch_bounds__(256) void k_res_ln2_proj(
    const float* __restrict__ x, const u32* __restrict__ PoT, const float* __restrict__ Pl,
    const float* __restrict__ ln2w, const float* __restrict__ ln2b,
    const float* __restrict__ piw,
    float* __restrict__ X2, float* __restrict__ Hbuf) {
  __shared__ float s1a[4 * 64], s2a[4 * 64];
  __shared__ __align__(16) short xn[64 * 72];  // [pos][c] bf16, 144B rows
  int t = threadIdx.x;
  int w = t >> 6;
  int p = t & 63;
  int q0 = blockIdx.x * 64;
  int q = q0 + p;
  int b = q / NPOS;
  int nn = q0 % NPOS;        // block-local spatial base (blocks never straddle batch)
  int n = q % NPOS;

  float lsum = 0.f;
#pragma unroll
  for (int s = 0; s < NSPLIT; ++s) lsum += Pl[(size_t)s * NTOT + q];
  float inv = 1.f / lsum;

  const float* xb = x + (size_t)b * CH * NPOS + n;
  float xr[16];
  float s1 = 0.f, s2 = 0.f;
#pragma unroll
  for (int j2 = 0; j2 < 8; ++j2) {
    float a0 = 0.f, a1 = 0.f;
#pragma unroll
    for (int s = 0; s < NSPLIT; ++s) {
      u32 v = PoT[((size_t)(s * 32 + w * 8 + j2)) * NTOT + q];
      a0 += __builtin_bit_cast(float, v << 16);
      a1 += __builtin_bit_cast(float, v & 0xffff0000u);
    }
    int cl = 2 * j2;
    int c = w * 16 + cl;
    float v0 = xb[(size_t)c * NPOS] + a0 * inv;
    float v1 = xb[(size_t)(c + 1) * NPOS] + a1 * inv;
    xr[cl] = v0; xr[cl + 1] = v1;
    s1 += v0 + v1;
    s2 += v0 * v0 + v1 * v1;
  }
  s1a[w * 64 + p] = s1;
  s2a[w * 64 + p] = s2;
  {
    float* xo = X2 + (size_t)b * CH * NPOS + n;
#pragma unroll
    for (int cl = 0; cl < 16; ++cl) xo[(size_t)(w * 16 + cl) * NPOS] = xr[cl];
  }
  __syncthreads();
  float mu = 0.f, m2 = 0.f;
#pragma unroll
  for (int ww = 0; ww < 4; ++ww) { mu += s1a[ww * 64 + p]; m2 += s2a[ww * 64 + p]; }
  mu *= (1.f / 64.f);
  float var = m2 * (1.f / 64.f) - mu * mu;
  float rstd = rsqrtf(var + 1e-5f);
  {
    u32* xw = (u32*)xn;
#pragma unroll
    for (int j2 = 0; j2 < 8; ++j2) {
      int cl = 2 * j2, c = w * 16 + cl;
      float y0 = (xr[cl] - mu) * rstd * ln2w[c] + ln2b[c];
      float y1 = (xr[cl + 1] - mu) * rstd * ln2w[c + 1] + ln2b[c + 1];
      u32 pk = ((u32)(unsigned short)f2bf(y1) << 16) | (u32)(unsigned short)f2bf(y0);
      xw[p * 36 + w * 8 + j2] = pk;
    }
  }
  __syncthreads();
  // Phase 2: MFMA. wave w -> oc group w*16. A = W rows, B = xn rows.
  int lane = t & 63;
  int L = lane & 15, quad = lane >> 4;
  bf16x8 a0, a1;
  {
    const float* wr = piw + (w * 16 + L) * 64 + quad * 8;
#pragma unroll
    for (int j = 0; j < 8; ++j) { a0[j] = f2bf(wr[j]); a1[j] = f2bf(wr[32 + j]); }
  }
  float* hb = Hbuf + (size_t)b * CH * NPOS + nn;
#pragma unroll
  for (int pt = 0; pt < 4; ++pt) {
    bf16x8 b0 = *(const bf16x8*)(xn + (pt * 16 + L) * 72 + quad * 8);
    bf16x8 b1 = *(const bf16x8*)(xn + (pt * 16 + L) * 72 + 32 + quad * 8);
    f32x4 acc = {0.f, 0.f, 0.f, 0.f};
    acc = __builtin_amdgcn_mfma_f32_16x16x32_bf16(a0, b0, acc, 0, 0, 0);
    acc = __builtin_amdgcn_mfma_f32_16x16x32_bf16(a1, b1, acc, 0, 0, 0);
#pragma unroll
    for (int i = 0; i < 4; ++i)
      hb[(size_t)(w * 16 + quad * 4 + i) * NPOS + pt * 16 + L] = acc[i];
  }
}

// ---------------- Kernel D: per-patch spectral filter ----------------
// grid (288) x 64.
__global__ __launch_bounds__(64) void k_fft(float* __restrict__ Hbuf, const float* __restrict__ fftw) {
  int idx = blockIdx.x * 64 + threadIdx.x;
  int wb = idx % 12;
  int t = idx / 12;
  int hb = t % 12;
  int t2 = t / 12;
  int c = t2 % 64;
  int b = t2 / 64;
  float* base = Hbuf + (size_t)(b * CH + c) * NPOS + (hb * 8) * 96 + wb * 8;
  const float r = 0.70710678118654752440f;
  const float CO[8] = {1.f, r, 0.f, -r, -1.f, -r, 0.f, r};
  const float SI[8] = {0.f, r, 1.f, r, 0.f, -r, -1.f, -r};
  float Ar[8][5], Ai[8][5];
#pragma unroll
  for (int p = 0; p < 8; ++p) {
    f32x4 ra = *(const f32x4*)(base + p * 96);
    f32x4 rb = *(const f32x4*)(base + p * 96 + 4);
    float row[8] = {ra[0], ra[1], ra[2], ra[3], rb[0], rb[1], rb[2], rb[3]};
#pragma unroll
    for (int v = 0; v < 5; ++v) {
      float sr = 0.f, si = 0.f;
#pragma unroll
      for (int q = 0; q < 8; ++q) {
        int k = (q * v) & 7;
        sr += row[q] * CO[k];
        si -= row[q] * SI[k];
      }
      Ar[p][v] = sr;
      Ai[p][v] = si;
    }
  }
  const float* wp = fftw + c * 40;
#pragma unroll
  for (int v = 0; v < 5; ++v) {
    float Br[8], Bi[8];
#pragma unroll
    for (int u = 0; u < 8; ++u) {
      float cr = 0.f, ci = 0.f;
#pragma unroll
      for (int p = 0; p < 8; ++p) {
        int k = (p * u) & 7;
        float cc = CO[k], ss = SI[k];
        cr += Ar[p][v] * cc + Ai[p][v] * ss;
        ci += Ai[p][v] * cc - Ar[p][v] * ss;
      }
      float wv = wp[u * 5 + v];
      Br[u] = cr * wv;
      Bi[u] = ci * wv;
    }
#pragma unroll
    for (int p = 0; p < 8; ++p) {
      float yr = 0.f, yi = 0.f;
#pragma unroll
      for (int u = 0; u < 8; ++u) {
        int k = (p * u) & 7;
        float cc = CO[k], ss = SI[k];
        yr += Br[u] * cc - Bi[u] * ss;
        yi += Bi[u] * cc + Br[u] * ss;
      }
      Ar[p][v] = yr * 0.125f;
      Ai[p][v] = yi * 0.125f;
    }
  }
#pragma unroll
  for (int p = 0; p < 8; ++p) {
    float outv[8];
#pragma unroll
    for (int q = 0; q < 8; ++q) {
      float acc = Ar[p][0] + ((q & 1) ? -Ar[p][4] : Ar[p][4]);
#pragma unroll
      for (int v = 1; v < 4; ++v) {
        int k = (q * v) & 7;
        acc += 2.f * (Ar[p][v] * CO[k] - Ai[p][v] * SI[k]);
      }
      outv[q] = acc * 0.125f;
    }
    f32x4 wa = {outv[0], outv[1], outv[2], outv[3]};
    f32x4 wb2 = {outv[4], outv[5], outv[6], outv[7]};
    *(f32x4*)(base + p * 96) = wa;
    *(f32x4*)(base + p * 96 + 4) = wb2;
  }
}

// ---------------- Kernel E1: dwconv3x3 + gelu-gate -> G ----------------
// grid (72, 32) x 256.
__global__ __launch_bounds__(256) void k_dw_gate(
    const float* __restrict__ Hbuf, const float* __restrict__ dww,
    float* __restrict__ G) {
  int cc = blockIdx.y;
  int q = blockIdx.x * 256 + threadIdx.x;
  int b = q / NPOS, n = q % NPOS;
  int y = n / 96, xx = n % 96;
  const float* h1 = Hbuf + (size_t)(b * CH + cc) * NPOS;
  const float* h2 = Hbuf + (size_t)(b * CH + cc + 32) * NPOS;
  float wd1[9], wd2[9];
#pragma unroll
  for (int ki = 0; ki < 9; ++ki) { wd1[ki] = dww[cc * 9 + ki]; wd2[ki] = dww[(cc + 32) * 9 + ki]; }
  float d1 = 0.f, d2 = 0.f;
  for (int dy = -1; dy <= 1; ++dy) {
    int yy = y + dy;
    if (yy < 0 || yy >= 96) continue;
    for (int dx = -1; dx <= 1; ++dx) {
      int xv = xx + dx;
      if (xv < 0 || xv >= 96) continue;
      int ki = (dy + 1) * 3 + (dx + 1);
      d1 += h1[yy * 96 + xv] * wd1[ki];
      d2 += h2[yy * 96 + xv] * wd2[ki];
    }
  }
  G[(size_t)cc * NTOT + q] = gelu_exact(d1) * d2;
}

// ---------------- Kernel E2: proj_out + residual ----------------
// grid (72, 8) x 256.
__global__ __launch_bounds__(256) void k_proj_out(
    const float* __restrict__ G, const float* __restrict__ poww,
    const float* __restrict__ X2, float* __restrict__ out) {
  int og = blockIdx.y;
  int q = blockIdx.x * 256 + threadIdx.x;
  int b = q / NPOS, n = q % NPOS;
  float g[32];
#pragma unroll
  for (int cg = 0; cg < 32; ++cg) g[cg] = G[(size_t)cg * NTOT + q];
  const float* xr = X2 + (size_t)b * CH * NPOS + n;
  float* ob = out + (size_t)b * CH * NPOS + n;
#pragma unroll
  for (int j = 0; j < 8; ++j) {
    int oc = og * 8 + j;
    const float* prow = poww + oc * 32;
    float acc = xr[(size_t)oc * NPOS];
#pragma unroll
    for (int cg = 0; cg < 32; ++cg) acc += prow[cg] * g[cg];
    ob[(size_t)oc * NPOS] = acc;
  }
}

extern "C" void kernel_launch(void* const* d_in, const int* in_sizes, int n_in,
                              void* d_out, int out_size, void* d_ws, size_t ws_size,
                              hipStream_t stream) {
  const float* x    = (const float*)d_in[0];
  const float* ln1w = (const float*)d_in[1];
  const float* ln1b = (const float*)d_in[2];
  const float* ln2w = (const float*)d_in[3];
  const float* ln2b = (const float*)d_in[4];
  const float* qw   = (const float*)d_in[5];
  const float* qb   = (const float*)d_in[6];
  const float* kw   = (const float*)d_in[7];
  const float* kb   = (const float*)d_in[8];
  const float* vw   = (const float*)d_in[9];
  const float* vb   = (const float*)d_in[10];
  const float* fftw = (const float*)d_in[11];
  const float* piw  = (const float*)d_in[12];
  const float* dww  = (const float*)d_in[13];
  const float* poww = (const float*)d_in[14];

  short* Qg  = (short*)d_ws;                         // [NTOT][64] bf16
  short* Kg  = Qg + (size_t)NTOT * 64;               // [NTOT][64] bf16
  short* Vgt = Kg + (size_t)NTOT * 64;               // [64][NTOT] bf16 (transposed)
  u32*   PoT = (u32*)(Vgt + (size_t)NTOT * 64);      // [NSPLIT][32][NTOT] u32 (18.9 MB)
  float* Pl  = (float*)(PoT + (size_t)NSPLIT * 32 * NTOT);
  float* X2  = Pl + (size_t)NSPLIT * NTOT;
  float* Hbuf = X2 + (size_t)NTOT * 64;
  float* G   = Hbuf + (size_t)NTOT * 64;             // [32][NTOT]

  k_ln_qkv<<<dim3(72, 3, 2), 256, 0, stream>>>(x, ln1w, ln1b, qw, qb, kw, kb, vw, vb, Qg, Kg, Vgt);
  k_attn<<<dim3(72, 2, NSPLIT), 256, 0, stream>>>(Qg, Kg, Vgt, PoT, Pl);
  k_res_ln2_proj<<<dim3(288), 256, 0, stream>>>(x, PoT, Pl, ln2w, ln2b, piw, X2, Hbuf);
  k_fft<<<dim3(288), 64, 0, stream>>>(Hbuf, fftw);
  k_dw_gate<<<dim3(72, 32), 256, 0, stream>>>(Hbuf, dww, G);
  k_proj_out<<<dim3(72, 8), 256, 0, stream>>>(G, poww, X2, (float*)d_out);
}